// Round 1
// baseline (861.835 us; speedup 1.0000x reference)
//
#include <hip/hip_runtime.h>
#include <stdint.h>

#define B_ 4
#define N_ 49104
#define C_ 90
#define NTILES 768            // ceil(N_/64)
#define NCLS (B_ * C_)        // 360
#define CAP 4096
#define MAXK 100
#define NBINS 1024
#define THR 0.01f

// ---------- exact fp32 math matching the numpy/jax reference ----------
__device__ __forceinline__ float area_of(float y1, float x1, float y2, float x2) {
#pragma clang fp contract(off)
  return (y2 - y1) * (x2 - x1);
}

__device__ __forceinline__ bool iou_gt(float ay1, float ax1, float ay2, float ax2, float aa,
                                       float by1, float bx1, float by2, float bx2, float ba) {
#pragma clang fp contract(off)
  float y1 = fmaxf(ay1, by1);
  float x1 = fmaxf(ax1, bx1);
  float y2 = fminf(ay2, by2);
  float x2 = fminf(ax2, bx2);
  float inter = fmaxf(y2 - y1, 0.0f) * fmaxf(x2 - x1, 0.0f);
  float denom = aa + ba - inter + 1e-8f;   // ((a+b)-inter)+1e-8, fp add commutative bitwise
  return (inter / denom) > 0.1f;
}

__device__ __forceinline__ unsigned long long umax64(unsigned long long a, unsigned long long b) {
  return a > b ? a : b;
}

// ---------- kernel T: transpose [B,N,C] -> [B,C,N] for coalesced class reads ----------
__global__ __launch_bounds__(256) void transpose_kernel(const float* __restrict__ cls,
                                                        float* __restrict__ ts) {
  const int TILE = 64;
  int blk = blockIdx.x;
  int b = blk / NTILES;
  int tile = blk % NTILES;
  int n0 = tile * TILE;
  __shared__ float sm[TILE * C_];  // [nn][c]
  int nvalid = N_ - n0; if (nvalid > TILE) nvalid = TILE;
  int cnt = nvalid * C_;
  const float* src = cls + ((size_t)b * N_ + n0) * C_;
  for (int i = threadIdx.x; i < cnt; i += 256) sm[i] = src[i];
  __syncthreads();
  for (int i = threadIdx.x; i < C_ * TILE; i += 256) {
    int c = i / TILE, nn = i % TILE;
    if (nn < nvalid) ts[((size_t)b * C_ + c) * N_ + n0 + nn] = sm[nn * C_ + c];
  }
}

// ---------- kernel A: per (image,class) candidate select + sort + greedy NMS ----------
__global__ __launch_bounds__(256) void nms_kernel(const float* __restrict__ boxes,
                                                  const float* __restrict__ cls,
                                                  const float* __restrict__ ts, int use_ts,
                                                  unsigned long long* __restrict__ keepkeys,
                                                  int* __restrict__ nk_arr,
                                                  float* __restrict__ teff_arr,
                                                  int* __restrict__ fb_flag) {
  int gcls = blockIdx.x;           // b*C_ + c
  int b = gcls / C_, c = gcls % C_;
  const float* sbase; size_t sstride;
  if (use_ts) { sbase = ts + (size_t)gcls * N_; sstride = 1; }
  else        { sbase = cls + (size_t)b * N_ * C_ + c; sstride = C_; }

  __shared__ unsigned int hist[NBINS];
  __shared__ unsigned int gsum[256];
  __shared__ unsigned long long keys[CAP];
  __shared__ int sh_cnt;
  __shared__ float sh_teff;
  __shared__ unsigned int sh_total;

  int tid = threadIdx.x;
  for (int i = tid; i < NBINS; i += 256) hist[i] = 0u;
  if (tid == 0) sh_cnt = 0;
  __syncthreads();

  // pass 1: histogram of scores > THR (scores are in (0,1))
  for (int n = tid; n < N_; n += 256) {
    float s = sbase[(size_t)n * sstride];
    if (s > THR) {
      int bin = (int)(s * (float)NBINS);      // 1024*s exact (pow2 scale)
      if (bin < 0) bin = 0; if (bin > NBINS - 1) bin = NBINS - 1;
      atomicAdd(&hist[bin], 1u);
    }
  }
  __syncthreads();

  // threshold bin: minimal bcur with suffix-count <= CAP
  {
    unsigned int ms = hist[4 * tid] + hist[4 * tid + 1] + hist[4 * tid + 2] + hist[4 * tid + 3];
    gsum[tid] = ms;
  }
  __syncthreads();
  if (tid == 0) {
    unsigned int total = 0;
    for (int g = 0; g < 256; ++g) total += gsum[g];
    unsigned int suf = 0; int bcur = NBINS;
    for (int g = 255; g >= 0; --g) {
      if (suf + gsum[g] > CAP) {
        for (int bb = 4 * g + 3; bb >= 4 * g; --bb) {
          if (suf + hist[bb] > CAP) break;
          suf += hist[bb]; bcur = bb;
        }
        break;
      }
      suf += gsum[g]; bcur = 4 * g;
    }
    float teff;
    if (bcur >= NBINS) teff = 2.0f;                       // degenerate: full fallback
    else teff = fmaxf((float)bcur / (float)NBINS, THR);   // bins<=10 only when all fit
    sh_teff = teff;
    sh_total = total;
  }
  __syncthreads();
  float teff = sh_teff;

  // pass 2: compact candidates (score > teff) into LDS keys
  for (int n = tid; n < N_; n += 256) {
    float s = sbase[(size_t)n * sstride];
    if (s > teff) {
      int pos = atomicAdd(&sh_cnt, 1);
      if (pos < CAP) {
        unsigned int sb = __float_as_uint(s);
        keys[pos] = ((unsigned long long)sb << 32) |
                    (unsigned long long)(0xFFFFFFFFu - (unsigned int)n);
      }
    }
  }
  __syncthreads();
  int M = sh_cnt; if (M > CAP) M = CAP;
  unsigned int total = sh_total;
  for (int i = M + tid; i < CAP; i += 256) keys[i] = 0ull;
  // zero this class's keep slots (ws is poisoned 0xAA)
  for (int i = tid; i < MAXK; i += 256) keepkeys[(size_t)gcls * MAXK + i] = 0ull;
  __syncthreads();

  // bitonic sort, descending (score desc, anchor asc via key packing)
  for (int k = 2; k <= CAP; k <<= 1) {
    for (int j = k >> 1; j > 0; j >>= 1) {
      for (int t = tid; t < CAP / 2; t += 256) {
        int i1 = 2 * t - (t & (j - 1));
        int i2 = i1 | j;
        unsigned long long a = keys[i1], bb = keys[i2];
        bool descBlock = ((i1 & k) == 0);
        bool sw = descBlock ? (a < bb) : (a > bb);
        if (sw) { keys[i1] = bb; keys[i2] = a; }
      }
      __syncthreads();
    }
  }

  // greedy NMS: wave 0 only, kept boxes distributed across lanes in registers
  if (tid < 64) {
    int lane = tid;
    float k0y1 = 0, k0x1 = 0, k0y2 = 0, k0x2 = 0, k0a = 0;
    float k1y1 = 0, k1x1 = 0, k1y2 = 0, k1x2 = 0, k1a = 0;
    int nk = 0, a0slot = -1;
    const float4* bx4 = (const float4*)(boxes + (size_t)b * N_ * 4);

    float4 cb = make_float4(0, 0, 0, 0);
    if (M > 0) cb = bx4[0xFFFFFFFFu - (unsigned int)(keys[0] & 0xFFFFFFFFull)];
    for (int i = 0; i < M; ++i) {
      unsigned long long key = keys[i];
      unsigned int anchor = 0xFFFFFFFFu - (unsigned int)(key & 0xFFFFFFFFull);
      float4 cur = cb;
      if (i + 1 < M)  // prefetch next candidate's box
        cb = bx4[0xFFFFFFFFu - (unsigned int)(keys[i + 1] & 0xFFFFFFFFull)];
      float ca = area_of(cur.x, cur.y, cur.z, cur.w);
      bool ov = false;
      if (lane < nk)      ov = iou_gt(k0y1, k0x1, k0y2, k0x2, k0a, cur.x, cur.y, cur.z, cur.w, ca);
      if (lane + 64 < nk) ov = ov || iou_gt(k1y1, k1x1, k1y2, k1x2, k1a, cur.x, cur.y, cur.z, cur.w, ca);
      if (__ballot(ov) == 0ull) {
        if (nk < 64) { if (lane == nk)      { k0y1 = cur.x; k0x1 = cur.y; k0y2 = cur.z; k0x2 = cur.w; k0a = ca; } }
        else         { if (lane == nk - 64) { k1y1 = cur.x; k1x1 = cur.y; k1y2 = cur.z; k1x2 = cur.w; k1a = ca; } }
        if (lane == 0) {
          unsigned int flat = anchor * C_ + (unsigned int)c;
          keepkeys[(size_t)gcls * MAXK + nk] =
              (key & 0xFFFFFFFF00000000ull) | (unsigned long long)(0xFFFFFFFFu - flat);
        }
        if (anchor == 0u) a0slot = nk;
        ++nk;
        if (nk == MAXK) break;
      }
    }
    if (lane == 0) {
      int fb = 0;
      if (nk < MAXK) {
        if ((unsigned int)M == total) {
          // reference exhaustion quirk: keep[0] = False when scores all -inf
          if (a0slot >= 0) keepkeys[(size_t)gcls * MAXK + a0slot] = 0ull;
        } else {
          fb = 1;  // candidates below teff remain: exact continuation needed
        }
      }
      fb_flag[gcls] = fb;
      nk_arr[gcls] = nk;
      teff_arr[gcls] = teff;
    }
  }
}

// ---------- kernel B: exact brute-force continuation (cold path, ~never taken) ----------
__global__ __launch_bounds__(256) void fallback_kernel(const float* __restrict__ boxes,
                                                       const float* __restrict__ cls,
                                                       const float* __restrict__ ts, int use_ts,
                                                       unsigned long long* __restrict__ keepkeys,
                                                       int* __restrict__ nk_arr,
                                                       float* __restrict__ teff_arr,
                                                       int* __restrict__ fb_flag) {
  int gcls = blockIdx.x;
  if (fb_flag[gcls] == 0) return;
  int b = gcls / C_, c = gcls % C_;
  const float* sbase; size_t sstride;
  if (use_ts) { sbase = ts + (size_t)gcls * N_; sstride = 1; }
  else        { sbase = cls + (size_t)b * N_ * C_ + c; sstride = C_; }
  float teff = teff_arr[gcls];
  int nk = nk_arr[gcls];
  unsigned long long* kk = keepkeys + (size_t)gcls * MAXK;
  const float* bx = boxes + (size_t)b * N_ * 4;

  __shared__ float ky1[MAXK], kx1[MAXK], ky2[MAXK], kx2[MAXK], kar[MAXK];
  __shared__ unsigned long long red[256];
  int tid = threadIdx.x;
  for (int j = tid; j < nk; j += 256) {
    unsigned int flat = 0xFFFFFFFFu - (unsigned int)(kk[j] & 0xFFFFFFFFull);
    unsigned int anchor = flat / C_;
    float y1 = bx[(size_t)anchor * 4 + 0], x1 = bx[(size_t)anchor * 4 + 1];
    float y2 = bx[(size_t)anchor * 4 + 2], x2 = bx[(size_t)anchor * 4 + 3];
    ky1[j] = y1; kx1[j] = x1; ky2[j] = y2; kx2[j] = x2; kar[j] = area_of(y1, x1, y2, x2);
  }
  __syncthreads();

  while (nk < MAXK) {
    unsigned long long best = 0ull;
    for (int n = tid; n < N_; n += 256) {
      float s = sbase[(size_t)n * sstride];
      if (s > THR && s <= teff) {
        float y1 = bx[(size_t)n * 4 + 0], x1 = bx[(size_t)n * 4 + 1];
        float y2 = bx[(size_t)n * 4 + 2], x2 = bx[(size_t)n * 4 + 3];
        float ar = area_of(y1, x1, y2, x2);
        bool ov = false;
        for (int j = 0; j < nk; ++j) {
          if (iou_gt(ky1[j], kx1[j], ky2[j], kx2[j], kar[j], y1, x1, y2, x2, ar)) { ov = true; break; }
        }
        if (!ov) {
          unsigned long long key = ((unsigned long long)__float_as_uint(s) << 32) |
                                   (unsigned long long)(0xFFFFFFFFu - (unsigned int)n);
          best = umax64(best, key);
        }
      }
    }
    red[tid] = best;
    __syncthreads();
    for (int sft = 128; sft > 0; sft >>= 1) {
      if (tid < sft) red[tid] = umax64(red[tid], red[tid + sft]);
      __syncthreads();
    }
    unsigned long long sel = red[0];
    __syncthreads();
    if (sel == 0ull) {
      if (tid == 0) {  // exhausted before MAXK: keep[0] = False
        unsigned int target = 0xFFFFFFFFu - (unsigned int)c;  // anchor 0 -> flat == c
        for (int j = 0; j < nk; ++j)
          if ((unsigned int)(kk[j] & 0xFFFFFFFFull) == target) kk[j] = 0ull;
      }
      break;
    }
    unsigned int anchor = 0xFFFFFFFFu - (unsigned int)(sel & 0xFFFFFFFFull);
    if (tid == 0) {
      float y1 = bx[(size_t)anchor * 4 + 0], x1 = bx[(size_t)anchor * 4 + 1];
      float y2 = bx[(size_t)anchor * 4 + 2], x2 = bx[(size_t)anchor * 4 + 3];
      ky1[nk] = y1; kx1[nk] = x1; ky2[nk] = y2; kx2[nk] = x2; kar[nk] = area_of(y1, x1, y2, x2);
      unsigned int flat = anchor * C_ + (unsigned int)c;
      kk[nk] = (sel & 0xFFFFFFFF00000000ull) | (unsigned long long)(0xFFFFFFFFu - flat);
    }
    ++nk;
    __syncthreads();
  }
  if (tid == 0) nk_arr[gcls] = nk;
}

// ---------- kernel C: per-image top-100 across all classes (stable tie-break) ----------
__global__ __launch_bounds__(256) void merge_kernel(const float* __restrict__ boxes,
                                                    const unsigned long long* __restrict__ keepkeys,
                                                    float* __restrict__ out) {
  int b = blockIdx.x;
  int tid = threadIdx.x;
  const unsigned long long* kk = keepkeys + (size_t)b * C_ * MAXK;
  const int TOT = C_ * MAXK;  // 9000
  unsigned long long lk[36];
#pragma unroll
  for (int i = 0; i < 36; ++i) {
    int idx = tid + i * 256;
    lk[i] = (idx < TOT) ? kk[idx] : 0ull;
  }
  __shared__ unsigned long long wred[4];
  __shared__ unsigned long long sel_sh;
  unsigned long long prev = 0xFFFFFFFFFFFFFFFFull;

  for (int r = 0; r < MAXK; ++r) {
    unsigned long long best = 0ull;
#pragma unroll
    for (int i = 0; i < 36; ++i) {
      unsigned long long v = lk[i];
      if (v < prev && v > best) best = v;
    }
    for (int m = 1; m < 64; m <<= 1) best = umax64(best, __shfl_xor(best, m));
    if ((tid & 63) == 0) wred[tid >> 6] = best;
    __syncthreads();
    if (tid == 0) {
      unsigned long long s = umax64(umax64(wred[0], wred[1]), umax64(wred[2], wred[3]));
      sel_sh = s;
      float oy1, ox1, oy2, ox2, sc, lb;
      if (s != 0ull) {
        unsigned int flat = 0xFFFFFFFFu - (unsigned int)(s & 0xFFFFFFFFull);
        unsigned int anchor = flat / C_;
        unsigned int label = flat - anchor * C_;
        sc = __uint_as_float((unsigned int)(s >> 32));
        const float* bp = boxes + ((size_t)b * N_ + anchor) * 4;
        oy1 = bp[0]; ox1 = bp[1]; oy2 = bp[2]; ox2 = bp[3];
        lb = (float)label;
      } else {
        oy1 = ox1 = oy2 = ox2 = -1.0f; sc = -1.0f; lb = -1.0f;
      }
      float* bo = out + ((size_t)b * MAXK + r) * 4;
      bo[0] = oy1; bo[1] = ox1; bo[2] = oy2; bo[3] = ox2;
      out[(size_t)B_ * MAXK * 4 + b * MAXK + r] = sc;
      out[(size_t)B_ * MAXK * 4 + B_ * MAXK + b * MAXK + r] = lb;
    }
    __syncthreads();
    prev = sel_sh;
  }
}

extern "C" void kernel_launch(void* const* d_in, const int* in_sizes, int n_in,
                              void* d_out, int out_size, void* d_ws, size_t ws_size,
                              hipStream_t stream) {
  const float* boxes = (const float*)d_in[0];          // [B,N,4]
  const float* cls = (const float*)d_in[1];            // [B,N,C]
  char* ws = (char*)d_ws;
  unsigned long long* keepkeys = (unsigned long long*)ws;       // 360*100*8 = 288000 B
  int* nk_arr = (int*)(ws + 288000);                            // 1440 B
  float* teff_arr = (float*)(ws + 288000 + 1440);               // 1440 B
  int* fb_flag = (int*)(ws + 288000 + 2880);                    // 1440 B
  const size_t ts_off = 292352;                                 // 256-aligned
  float* ts = (float*)(ws + ts_off);
  size_t need = ts_off + (size_t)B_ * C_ * N_ * sizeof(float);
  int use_ts = (ws_size >= need) ? 1 : 0;

  if (use_ts)
    transpose_kernel<<<B_ * NTILES, 256, 0, stream>>>(cls, ts);
  nms_kernel<<<NCLS, 256, 0, stream>>>(boxes, cls, ts, use_ts, keepkeys, nk_arr, teff_arr, fb_flag);
  fallback_kernel<<<NCLS, 256, 0, stream>>>(boxes, cls, ts, use_ts, keepkeys, nk_arr, teff_arr, fb_flag);
  merge_kernel<<<B_, 256, 0, stream>>>(boxes, keepkeys, (float*)d_out);
}

// Round 2
// 498.638 us; speedup vs baseline: 1.7284x; 1.7284x over previous
//
#include <hip/hip_runtime.h>
#include <stdint.h>

typedef unsigned long long u64;

#define B_ 4
#define N_ 49104
#define C_ 90
#define NCLS (B_ * C_)        // 360
#define MAXK 100
#define THR 0.01f
#define CHK 512               // chunk sort size
#define NB2 2048              // fine histogram bins (score_bits[22:12])

// ---------- exact fp32 math matching the numpy/jax reference ----------
__device__ __forceinline__ float area_of(float y1, float x1, float y2, float x2) {
#pragma clang fp contract(off)
  return (y2 - y1) * (x2 - x1);
}

__device__ __forceinline__ bool iou_gt(float ay1, float ax1, float ay2, float ax2, float aa,
                                       float by1, float bx1, float by2, float bx2, float ba) {
#pragma clang fp contract(off)
  float y1 = fmaxf(ay1, by1);
  float x1 = fmaxf(ax1, bx1);
  float y2 = fminf(ay2, by2);
  float x2 = fminf(ax2, bx2);
  float inter = fmaxf(y2 - y1, 0.0f) * fmaxf(x2 - x1, 0.0f);
  float denom = aa + ba - inter + 1e-8f;
  return (inter / denom) > 0.1f;
}

__device__ __forceinline__ u64 umax64(u64 a, u64 b) { return a > b ? a : b; }

__device__ __forceinline__ u64 shfl_xor_u64(u64 v, int m) {
  int lo = __shfl_xor((int)(unsigned)v, m);
  int hi = __shfl_xor((int)(unsigned)(v >> 32), m);
  return ((u64)(unsigned)hi << 32) | (u64)(unsigned)lo;
}

// ---------- kernel S: one coalesced pass, append candidates per (b,c) ----------
__global__ __launch_bounds__(256) void select_kernel(const float* __restrict__ cls,
                                                     u64* __restrict__ keybuf,
                                                     unsigned* __restrict__ cnt,
                                                     int capsel, float t0) {
  const int NC = N_ * C_;               // 4,419,360 (divisible by 4; f4 never crosses image)
  const int nf4 = (B_ * NC) / 4;
  const float4* src = (const float4*)cls;
  for (int i = blockIdx.x * 256 + threadIdx.x; i < nf4; i += gridDim.x * 256) {
    float4 v = src[i];
    int flat0 = i * 4;
    float sv[4] = {v.x, v.y, v.z, v.w};
#pragma unroll
    for (int e = 0; e < 4; ++e) {
      float s = sv[e];
      if (s > t0) {
        unsigned flat = (unsigned)(flat0 + e);
        unsigned b = flat / (unsigned)NC;
        unsigned rem = flat - b * (unsigned)NC;
        unsigned n = rem / (unsigned)C_;
        unsigned c = rem - n * (unsigned)C_;
        unsigned g = b * C_ + c;
        unsigned pos = atomicAdd(&cnt[g * 16], 1u);   // 64B-padded counters
        if (pos < (unsigned)capsel)
          keybuf[(size_t)g * capsel + pos] =
              ((u64)__float_as_uint(s) << 32) | (u64)(0xFFFFFFFFu - n);
      }
    }
  }
}

// ---------- kernel A: per-class chunked partial sort + serial greedy NMS ----------
__global__ __launch_bounds__(256) void nms_kernel(const float* __restrict__ boxes,
                                                  const u64* __restrict__ keybuf,
                                                  const unsigned* __restrict__ cnt,
                                                  int capsel, float t0,
                                                  u64* __restrict__ keepkeys,
                                                  int* __restrict__ nk_arr,
                                                  float* __restrict__ teff_arr,
                                                  int* __restrict__ fb_flag) {
  int gcls = blockIdx.x;
  int b = gcls / C_, c = gcls - b * C_;
  __shared__ u64 karr[4096];
  __shared__ unsigned hist[NB2];
  __shared__ u64 ck[CHK];
  __shared__ int sh_blo, sh_run, sh_nk, sh_cc, sh_over;
  int tid = threadIdx.x;

  for (int i = tid; i < MAXK; i += 256) keepkeys[(size_t)gcls * MAXK + i] = 0ull;

  unsigned Mraw = cnt[gcls * 16];
  if (Mraw > (unsigned)capsel) {        // selection buffer overflow: full brute force (never)
    if (tid == 0) { nk_arr[gcls] = 0; teff_arr[gcls] = 2.0f; fb_flag[gcls] = 1; }
    return;
  }
  int M = (int)Mraw;

  for (int i = tid; i < NB2; i += 256) hist[i] = 0u;
  if (tid == 0) { sh_nk = 0; sh_over = 0; }
  __syncthreads();

  const u64* src = keybuf + (size_t)gcls * capsel;
  for (int i = tid; i < M; i += 256) {
    u64 k = src[i];
    karr[i] = k;
    atomicAdd(&hist[(unsigned)(k >> 44) & (NB2 - 1)], 1u);   // bin = score_bits[22:12]
  }
  __syncthreads();

  // persistent greedy state lives in wave-0 registers across chunk iterations
  float k0y1 = 0, k0x1 = 0, k0y2 = 0, k0x2 = 0, k0a = 0;
  float k1y1 = 0, k1x1 = 0, k1y2 = 0, k1x2 = 0, k1a = 0;
  int nk = 0;
  const float4* bx4 = (const float4*)(boxes + (size_t)b * N_ * 4);

  int bhi = NB2, ext = 0;
  while (ext < M && sh_nk < MAXK) {
    if (tid == 0) {
      int rem = M - ext, run = 0, bb = bhi;
      while (bb > 0) {
        unsigned h = hist[bb - 1];
        if (run + (int)h > CHK) break;
        run += (int)h; --bb;
        if (run >= 480 || run >= rem) break;
      }
      if (run == 0) sh_over = 1;        // a single bin holds >CHK keys (never for uniform)
      sh_blo = bb; sh_run = run; sh_cc = 0;
    }
    __syncthreads();
    if (sh_over) break;
    int blo = sh_blo, run = sh_run;

    // compact keys with bin in [blo, bhi)
    for (int i = tid; i < M; i += 256) {
      u64 k = karr[i];
      int bin = (int)((unsigned)(k >> 44) & (NB2 - 1));
      if (bin >= blo && bin < bhi) { int p = atomicAdd(&sh_cc, 1); ck[p] = k; }
    }
    for (int i = run + tid; i < CHK; i += 256) ck[i] = 0ull;
    __syncthreads();

    // bitonic sort CHK keys descending (score desc, anchor asc via ~n packing)
    for (int kk2 = 2; kk2 <= CHK; kk2 <<= 1) {
      for (int j = kk2 >> 1; j > 0; j >>= 1) {
        if (tid < CHK / 2) {
          int i1 = 2 * tid - (tid & (j - 1));
          int i2 = i1 | j;
          u64 a = ck[i1], bb2 = ck[i2];
          bool desc = ((i1 & kk2) == 0);
          bool sw = desc ? (a < bb2) : (a > bb2);
          if (sw) { ck[i1] = bb2; ck[i2] = a; }
        }
        __syncthreads();
      }
    }

    // serial greedy on wave 0; kept boxes distributed across lanes in registers
    if (tid < 64) {
      int lane = tid;
      float4 cb = make_float4(0, 0, 0, 0);
      if (run > 0) cb = bx4[0xFFFFFFFFu - (unsigned)(ck[0] & 0xFFFFFFFFull)];
      for (int i = 0; i < run; ++i) {
        u64 key = ck[i];
        unsigned anchor = 0xFFFFFFFFu - (unsigned)(key & 0xFFFFFFFFull);
        float4 cur = cb;
        if (i + 1 < run) cb = bx4[0xFFFFFFFFu - (unsigned)(ck[i + 1] & 0xFFFFFFFFull)];
        float ca = area_of(cur.x, cur.y, cur.z, cur.w);
        bool ov = false;
        if (lane < nk)      ov = iou_gt(k0y1, k0x1, k0y2, k0x2, k0a, cur.x, cur.y, cur.z, cur.w, ca);
        if (lane + 64 < nk) ov = ov || iou_gt(k1y1, k1x1, k1y2, k1x2, k1a, cur.x, cur.y, cur.z, cur.w, ca);
        if (__ballot(ov) == 0ull) {
          if (nk < 64) { if (lane == nk)      { k0y1 = cur.x; k0x1 = cur.y; k0y2 = cur.z; k0x2 = cur.w; k0a = ca; } }
          else         { if (lane == nk - 64) { k1y1 = cur.x; k1x1 = cur.y; k1y2 = cur.z; k1x2 = cur.w; k1a = ca; } }
          if (lane == 0) {
            unsigned flat = anchor * C_ + (unsigned)c;
            keepkeys[(size_t)gcls * MAXK + nk] =
                (key & 0xFFFFFFFF00000000ull) | (u64)(0xFFFFFFFFu - flat);
          }
          ++nk;
          if (nk == MAXK) break;
        }
      }
      if (lane == 0) sh_nk = nk;
    }
    __syncthreads();
    ext += run;
    bhi = blo;
  }

  if (tid == 0) {       // tid 0 == lane 0 of wave 0: nk is authoritative here
    nk_arr[gcls] = nk;
    int fb = 0; float teff = t0;
    if (nk < MAXK) {
      fb = 1;
      if (sh_over)      // remaining keys all have score_bits < (bhi<<12); exp bits = 126
        teff = __uint_as_float(0x3F000000u | (((unsigned)bhi << 12) - 1u));
    }
    fb_flag[gcls] = fb;
    teff_arr[gcls] = teff;
  }
}

// ---------- kernel B: exact brute-force continuation (cold path) ----------
__global__ __launch_bounds__(256) void fallback_kernel(const float* __restrict__ boxes,
                                                       const float* __restrict__ cls,
                                                       u64* __restrict__ keepkeys,
                                                       int* __restrict__ nk_arr,
                                                       float* __restrict__ teff_arr,
                                                       int* __restrict__ fb_flag) {
  int gcls = blockIdx.x;
  if (fb_flag[gcls] == 0) return;
  int b = gcls / C_, c = gcls - b * C_;
  const float* sbase = cls + (size_t)b * N_ * C_ + c;
  float teff = teff_arr[gcls];
  int nk = nk_arr[gcls];
  u64* kk = keepkeys + (size_t)gcls * MAXK;
  const float* bx = boxes + (size_t)b * N_ * 4;

  __shared__ float ky1[MAXK], kx1[MAXK], ky2[MAXK], kx2[MAXK], kar[MAXK];
  __shared__ u64 red[256];
  int tid = threadIdx.x;
  for (int j = tid; j < nk; j += 256) {
    unsigned flat = 0xFFFFFFFFu - (unsigned)(kk[j] & 0xFFFFFFFFull);
    unsigned anchor = flat / C_;
    float y1 = bx[(size_t)anchor * 4 + 0], x1 = bx[(size_t)anchor * 4 + 1];
    float y2 = bx[(size_t)anchor * 4 + 2], x2 = bx[(size_t)anchor * 4 + 3];
    ky1[j] = y1; kx1[j] = x1; ky2[j] = y2; kx2[j] = x2; kar[j] = area_of(y1, x1, y2, x2);
  }
  __syncthreads();

  while (nk < MAXK) {
    u64 best = 0ull;
    for (int n = tid; n < N_; n += 256) {
      float s = sbase[(size_t)n * C_];
      if (s > THR && s <= teff) {
        float y1 = bx[(size_t)n * 4 + 0], x1 = bx[(size_t)n * 4 + 1];
        float y2 = bx[(size_t)n * 4 + 2], x2 = bx[(size_t)n * 4 + 3];
        float ar = area_of(y1, x1, y2, x2);
        bool ov = false;
        for (int j = 0; j < nk; ++j) {
          if (iou_gt(ky1[j], kx1[j], ky2[j], kx2[j], kar[j], y1, x1, y2, x2, ar)) { ov = true; break; }
        }
        if (!ov) {
          u64 key = ((u64)__float_as_uint(s) << 32) | (u64)(0xFFFFFFFFu - (unsigned)n);
          best = umax64(best, key);
        }
      }
    }
    red[tid] = best;
    __syncthreads();
    for (int sft = 128; sft > 0; sft >>= 1) {
      if (tid < sft) red[tid] = umax64(red[tid], red[tid + sft]);
      __syncthreads();
    }
    u64 sel = red[0];
    __syncthreads();
    if (sel == 0ull) {
      if (tid == 0) {  // exhausted before MAXK: reference quirk -> keep[anchor 0] = False
        unsigned target = 0xFFFFFFFFu - (unsigned)c;  // anchor 0 -> flat == c
        for (int j = 0; j < nk; ++j)
          if ((unsigned)(kk[j] & 0xFFFFFFFFull) == target) kk[j] = 0ull;
      }
      break;
    }
    unsigned anchor = 0xFFFFFFFFu - (unsigned)(sel & 0xFFFFFFFFull);
    if (tid == 0) {
      float y1 = bx[(size_t)anchor * 4 + 0], x1 = bx[(size_t)anchor * 4 + 1];
      float y2 = bx[(size_t)anchor * 4 + 2], x2 = bx[(size_t)anchor * 4 + 3];
      ky1[nk] = y1; kx1[nk] = x1; ky2[nk] = y2; kx2[nk] = x2; kar[nk] = area_of(y1, x1, y2, x2);
      unsigned flat = anchor * C_ + (unsigned)c;
      kk[nk] = (sel & 0xFFFFFFFF00000000ull) | (u64)(0xFFFFFFFFu - flat);
    }
    ++nk;
    __syncthreads();
  }
  if (tid == 0) nk_arr[gcls] = nk;
}

// ---------- kernel C: 90-way sorted-list merge, one wave per image ----------
#define PRE 32
__global__ __launch_bounds__(64) void merge_kernel(const float* __restrict__ boxes,
                                                   const u64* __restrict__ keepkeys,
                                                   const int* __restrict__ nk_arr,
                                                   float* __restrict__ out) {
  int b = blockIdx.x;
  int lane = threadIdx.x;
  __shared__ u64 pk[C_ * PRE];
  __shared__ u64 selk[MAXK];
  const u64* kk = keepkeys + (size_t)b * C_ * MAXK;

  for (int i = lane; i < C_ * PRE; i += 64) {
    int cc = i / PRE, j = i - cc * PRE;
    pk[i] = kk[(size_t)cc * MAXK + j];
  }
  __syncthreads();

  int c0 = lane, c1 = lane + 64;
  int len0 = (c0 < C_) ? nk_arr[b * C_ + c0] : 0;
  int len1 = (c1 < C_) ? nk_arr[b * C_ + c1] : 0;
  int h0 = 0, h1 = 0;

  auto fetchc = [&](int cc, int& h, int len) -> u64 {
    while (h < len) {
      u64 k = (h < PRE) ? pk[cc * PRE + h] : kk[(size_t)cc * MAXK + h];
      if (k != 0ull) return k;   // skip quirk-nulled holes
      ++h;
    }
    return 0ull;
  };
  u64 cand0 = (c0 < C_) ? fetchc(c0, h0, len0) : 0ull;
  u64 cand1 = (c1 < C_) ? fetchc(c1, h1, len1) : 0ull;

  for (int r = 0; r < MAXK; ++r) {
    u64 my = umax64(cand0, cand1);
    u64 g = my;
#pragma unroll
    for (int m = 1; m < 64; m <<= 1) g = umax64(g, shfl_xor_u64(g, m));
    if (lane == 0) selk[r] = g;
    if (g != 0ull && my == g) {          // unique keys: exactly one owner lane
      if (cand0 == g) { ++h0; cand0 = fetchc(c0, h0, len0); }
      else            { ++h1; cand1 = fetchc(c1, h1, len1); }
    }
  }
  __syncthreads();

  for (int r = lane; r < MAXK; r += 64) {
    u64 s = selk[r];
    float oy1, ox1, oy2, ox2, sc, lb;
    if (s != 0ull) {
      unsigned flat = 0xFFFFFFFFu - (unsigned)(s & 0xFFFFFFFFull);
      unsigned anchor = flat / C_;
      unsigned label = flat - anchor * C_;
      sc = __uint_as_float((unsigned)(s >> 32));
      const float4 bp = ((const float4*)(boxes + (size_t)b * N_ * 4))[anchor];
      oy1 = bp.x; ox1 = bp.y; oy2 = bp.z; ox2 = bp.w;
      lb = (float)label;
    } else {
      oy1 = ox1 = oy2 = ox2 = -1.0f; sc = -1.0f; lb = -1.0f;
    }
    float* bo = out + ((size_t)b * MAXK + r) * 4;
    bo[0] = oy1; bo[1] = ox1; bo[2] = oy2; bo[3] = ox2;
    out[(size_t)B_ * MAXK * 4 + b * MAXK + r] = sc;
    out[(size_t)B_ * MAXK * 4 + B_ * MAXK + b * MAXK + r] = lb;
  }
}

extern "C" void kernel_launch(void* const* d_in, const int* in_sizes, int n_in,
                              void* d_out, int out_size, void* d_ws, size_t ws_size,
                              hipStream_t stream) {
  const float* boxes = (const float*)d_in[0];   // [B,N,4]
  const float* cls = (const float*)d_in[1];     // [B,N,C]
  char* ws = (char*)d_ws;

  // pick capacity/threshold per available workspace (counters must stay safe)
  int capsel; float t0;
  auto need_for = [](int cap) -> size_t {
    return 23040 + (size_t)NCLS * cap * 8 + 288000 + 3 * 1440;
  };
  if (ws_size >= need_for(4096))      { capsel = 4096; t0 = 0.93f;  }  // M≈3437±57
  else if (ws_size >= need_for(2048)) { capsel = 2048; t0 = 0.962f; }  // M≈1866±42
  else                                { capsel = 1024; t0 = 0.985f; }  // M≈737±27

  unsigned* cnt = (unsigned*)ws;                                 // 360*16 u32 (64B padded)
  u64* keybuf = (u64*)(ws + 23040);
  size_t off = 23040 + (size_t)NCLS * capsel * 8;
  u64* keepkeys = (u64*)(ws + off);          off += 288000;
  int* nk_arr = (int*)(ws + off);            off += 1440;
  float* teff_arr = (float*)(ws + off);      off += 1440;
  int* fb_flag = (int*)(ws + off);

  hipMemsetAsync(cnt, 0, 23040, stream);
  select_kernel<<<2048, 256, 0, stream>>>(cls, keybuf, cnt, capsel, t0);
  nms_kernel<<<NCLS, 256, 0, stream>>>(boxes, keybuf, cnt, capsel, t0,
                                       keepkeys, nk_arr, teff_arr, fb_flag);
  fallback_kernel<<<NCLS, 256, 0, stream>>>(boxes, cls, keepkeys, nk_arr, teff_arr, fb_flag);
  merge_kernel<<<B_, 64, 0, stream>>>(boxes, keepkeys, nk_arr, (float*)d_out);
}

// Round 3
// 363.958 us; speedup vs baseline: 2.3680x; 1.3700x over previous
//
#include <hip/hip_runtime.h>
#include <stdint.h>

typedef unsigned long long u64;

#define B_ 4
#define N_ 49104
#define C_ 90
#define NCLS (B_ * C_)        // 360
#define MAXK 100
#define THR 0.01f
#define T0 0.93f              // fixed selection threshold: M ~ Binom(49104, .07) = 3437 +/- 57
#define CAPK 4096             // LDS candidate capacity (+11.6 sigma)
#define CHK 512               // chunk sort size
#define NB2 2048              // fine histogram bins (score_bits[22:12]; all cands share exp 126)
#define TTILE 128             // transpose tile (anchors)
#define NTT ((N_ + TTILE - 1) / TTILE)   // 384

// ---------- exact fp32 math matching the numpy/jax reference ----------
__device__ __forceinline__ float area_of(float y1, float x1, float y2, float x2) {
#pragma clang fp contract(off)
  return (y2 - y1) * (x2 - x1);
}

__device__ __forceinline__ bool iou_gt(float ay1, float ax1, float ay2, float ax2, float aa,
                                       float by1, float bx1, float by2, float bx2, float ba) {
#pragma clang fp contract(off)
  float y1 = fmaxf(ay1, by1);
  float x1 = fmaxf(ax1, bx1);
  float y2 = fminf(ay2, by2);
  float x2 = fminf(ax2, bx2);
  float inter = fmaxf(y2 - y1, 0.0f) * fmaxf(x2 - x1, 0.0f);
  float denom = aa + ba - inter + 1e-8f;
  return (inter / denom) > 0.1f;
}

__device__ __forceinline__ u64 umax64(u64 a, u64 b) { return a > b ? a : b; }

__device__ __forceinline__ u64 shfl_xor_u64(u64 v, int m) {
  int lo = __shfl_xor((int)(unsigned)v, m);
  int hi = __shfl_xor((int)(unsigned)(v >> 32), m);
  return ((u64)(unsigned)hi << 32) | (u64)(unsigned)lo;
}

// ---------- kernel T: [B,N,C] -> [B,C,N], LDS tile padded 90->91 (conflict-free) ----------
__global__ __launch_bounds__(256) void transpose_kernel(const float* __restrict__ cls,
                                                        float* __restrict__ ts) {
  int blk = blockIdx.x;
  int b = blk / NTT, tile = blk - b * NTT;
  int n0 = tile * TTILE;
  int nvalid = N_ - n0; if (nvalid > TTILE) nvalid = TTILE;
  __shared__ float sm[TTILE * 91];
  const float4* s4 = (const float4*)(cls + ((size_t)b * N_ + n0) * C_);  // 16B aligned
  int cnt4 = (nvalid * C_) >> 2;                                         // *90 divisible by 4
  for (int i = threadIdx.x; i < cnt4; i += 256) {
    float4 v = s4[i];
    int e0 = i * 4;
#pragma unroll
    for (int j = 0; j < 4; ++j) {
      int e = e0 + j;
      int nn = e / C_, c = e - nn * C_;
      sm[nn * 91 + c] = (&v.x)[j];
    }
  }
  __syncthreads();
  for (int i = threadIdx.x; i < C_ * TTILE; i += 256) {
    int c = i >> 7, nn = i & (TTILE - 1);
    if (nn < nvalid) ts[((size_t)b * C_ + c) * N_ + n0 + nn] = sm[nn * 91 + c];
  }
}

// ---------- kernel A: fused select (coalesced row) + chunked sort + greedy NMS ----------
__global__ __launch_bounds__(256) void nms_kernel(const float* __restrict__ boxes,
                                                  const float* __restrict__ cls,
                                                  const float* __restrict__ ts, int use_ts,
                                                  u64* __restrict__ keepkeys,
                                                  int* __restrict__ nk_arr,
                                                  float* __restrict__ teff_arr,
                                                  int* __restrict__ fb_flag) {
  int gcls = blockIdx.x;
  int b = gcls / C_, c = gcls - b * C_;
  __shared__ u64 karr[CAPK];
  __shared__ unsigned hist[NB2];
  __shared__ u64 ck[CHK];
  __shared__ int sh_blo, sh_run, sh_nk, sh_cc, sh_over;
  __shared__ unsigned sh_cnt;
  int tid = threadIdx.x;
  int lane = tid & 63;

  for (int i = tid; i < MAXK; i += 256) keepkeys[(size_t)gcls * MAXK + i] = 0ull;
  for (int i = tid; i < NB2; i += 256) hist[i] = 0u;
  if (tid == 0) { sh_cnt = 0u; sh_nk = 0; sh_over = 0; }
  __syncthreads();

  // --- selection: wave-aggregated append of (score, anchor) keys, score > T0 ---
  auto emit = [&](float s, unsigned n) {
    bool p = s > T0;
    u64 m = __ballot(p);
    if (m != 0ull) {
      int leader = __ffsll((long long)m) - 1;
      unsigned base = 0u;
      if (lane == leader) base = atomicAdd(&sh_cnt, (unsigned)__popcll(m));
      base = (unsigned)__shfl((int)base, leader);
      if (p) {
        unsigned pos = base + (unsigned)__popcll(m & ((1ull << lane) - 1ull));
        if (pos < CAPK) {
          u64 key = ((u64)__float_as_uint(s) << 32) | (u64)(0xFFFFFFFFu - n);
          karr[pos] = key;
          atomicAdd(&hist[(unsigned)(key >> 44) & (NB2 - 1)], 1u);
        }
      }
    }
  };
  if (use_ts) {
    const float4* row4 = (const float4*)(ts + (size_t)gcls * N_);  // N_*4B % 16 == 0
    for (int i4 = tid; i4 < N_ / 4; i4 += 256) {
      float4 v = row4[i4];
#pragma unroll
      for (int j = 0; j < 4; ++j) emit((&v.x)[j], (unsigned)(i4 * 4 + j));
    }
  } else {
    const float* sbase = cls + (size_t)b * N_ * C_ + c;
    for (int n = tid; n < N_; n += 256) emit(sbase[(size_t)n * C_], (unsigned)n);
  }
  __syncthreads();

  unsigned Mraw = sh_cnt;
  if (Mraw > CAPK) {     // overflow (p < 1e-25): full brute force fallback
    if (tid == 0) { nk_arr[gcls] = 0; teff_arr[gcls] = 2.0f; fb_flag[gcls] = 1; }
    return;
  }
  int M = (int)Mraw;

  // persistent greedy state lives in wave-0 registers across chunk iterations
  float k0y1 = 0, k0x1 = 0, k0y2 = 0, k0x2 = 0, k0a = 0;
  float k1y1 = 0, k1x1 = 0, k1y2 = 0, k1x2 = 0, k1a = 0;
  int nk = 0;
  const float4* bx4 = (const float4*)(boxes + (size_t)b * N_ * 4);

  int bhi = NB2, ext = 0;
  while (ext < M && sh_nk < MAXK) {
    if (tid == 0) {
      int rem = M - ext, run = 0, bb = bhi;
      while (bb > 0) {
        unsigned h = hist[bb - 1];
        if (run + (int)h > CHK) break;
        run += (int)h; --bb;
        if (run >= 480 || run >= rem) break;
      }
      if (run == 0) sh_over = 1;   // single bin > CHK keys (never for uniform scores)
      sh_blo = bb; sh_run = run; sh_cc = 0;
    }
    __syncthreads();
    if (sh_over) break;
    int blo = sh_blo, run = sh_run;

    // compact keys with bin in [blo, bhi)
    for (int i = tid; i < M; i += 256) {
      u64 k = karr[i];
      int bin = (int)((unsigned)(k >> 44) & (NB2 - 1));
      if (bin >= blo && bin < bhi) { int p = atomicAdd(&sh_cc, 1); ck[p] = k; }
    }
    for (int i = run + tid; i < CHK; i += 256) ck[i] = 0ull;
    __syncthreads();

    // bitonic sort CHK keys descending (score desc, anchor asc via ~n packing)
    for (int kk2 = 2; kk2 <= CHK; kk2 <<= 1) {
      for (int j = kk2 >> 1; j > 0; j >>= 1) {
        if (tid < CHK / 2) {
          int i1 = 2 * tid - (tid & (j - 1));
          int i2 = i1 | j;
          u64 a = ck[i1], bb2 = ck[i2];
          bool desc = ((i1 & kk2) == 0);
          bool sw = desc ? (a < bb2) : (a > bb2);
          if (sw) { ck[i1] = bb2; ck[i2] = a; }
        }
        __syncthreads();
      }
    }

    // serial greedy on wave 0; kept boxes distributed across lanes in registers
    if (tid < 64) {
      float4 cb = make_float4(0, 0, 0, 0);
      if (run > 0) cb = bx4[0xFFFFFFFFu - (unsigned)(ck[0] & 0xFFFFFFFFull)];
      for (int i = 0; i < run; ++i) {
        u64 key = ck[i];
        unsigned anchor = 0xFFFFFFFFu - (unsigned)(key & 0xFFFFFFFFull);
        float4 cur = cb;
        if (i + 1 < run) cb = bx4[0xFFFFFFFFu - (unsigned)(ck[i + 1] & 0xFFFFFFFFull)];
        float ca = area_of(cur.x, cur.y, cur.z, cur.w);
        bool ov = false;
        if (lane < nk)      ov = iou_gt(k0y1, k0x1, k0y2, k0x2, k0a, cur.x, cur.y, cur.z, cur.w, ca);
        if (lane + 64 < nk) ov = ov || iou_gt(k1y1, k1x1, k1y2, k1x2, k1a, cur.x, cur.y, cur.z, cur.w, ca);
        if (__ballot(ov) == 0ull) {
          if (nk < 64) { if (lane == nk)      { k0y1 = cur.x; k0x1 = cur.y; k0y2 = cur.z; k0x2 = cur.w; k0a = ca; } }
          else         { if (lane == nk - 64) { k1y1 = cur.x; k1x1 = cur.y; k1y2 = cur.z; k1x2 = cur.w; k1a = ca; } }
          if (lane == 0) {
            unsigned flat = anchor * C_ + (unsigned)c;
            keepkeys[(size_t)gcls * MAXK + nk] =
                (key & 0xFFFFFFFF00000000ull) | (u64)(0xFFFFFFFFu - flat);
          }
          ++nk;
          if (nk == MAXK) break;
        }
      }
      if (lane == 0) sh_nk = nk;
    }
    __syncthreads();
    ext += run;
    bhi = blo;
  }

  if (tid == 0) {
    nk_arr[gcls] = nk;
    int fb = 0; float teff = T0;
    if (nk < MAXK) {
      fb = 1;
      if (sh_over)   // remaining keys all below bin bhi; exponent bits = 126
        teff = __uint_as_float(0x3F000000u | (((unsigned)bhi << 12) - 1u));
    }
    fb_flag[gcls] = fb;
    teff_arr[gcls] = teff;
  }
}

// ---------- kernel B: exact brute-force continuation (cold path) ----------
__global__ __launch_bounds__(256) void fallback_kernel(const float* __restrict__ boxes,
                                                       const float* __restrict__ cls,
                                                       u64* __restrict__ keepkeys,
                                                       int* __restrict__ nk_arr,
                                                       float* __restrict__ teff_arr,
                                                       int* __restrict__ fb_flag) {
  int gcls = blockIdx.x;
  if (fb_flag[gcls] == 0) return;
  int b = gcls / C_, c = gcls - b * C_;
  const float* sbase = cls + (size_t)b * N_ * C_ + c;
  float teff = teff_arr[gcls];
  int nk = nk_arr[gcls];
  u64* kk = keepkeys + (size_t)gcls * MAXK;
  const float* bx = boxes + (size_t)b * N_ * 4;

  __shared__ float ky1[MAXK], kx1[MAXK], ky2[MAXK], kx2[MAXK], kar[MAXK];
  __shared__ u64 red[256];
  int tid = threadIdx.x;
  for (int j = tid; j < nk; j += 256) {
    unsigned flat = 0xFFFFFFFFu - (unsigned)(kk[j] & 0xFFFFFFFFull);
    unsigned anchor = flat / C_;
    float y1 = bx[(size_t)anchor * 4 + 0], x1 = bx[(size_t)anchor * 4 + 1];
    float y2 = bx[(size_t)anchor * 4 + 2], x2 = bx[(size_t)anchor * 4 + 3];
    ky1[j] = y1; kx1[j] = x1; ky2[j] = y2; kx2[j] = x2; kar[j] = area_of(y1, x1, y2, x2);
  }
  __syncthreads();

  while (nk < MAXK) {
    u64 best = 0ull;
    for (int n = tid; n < N_; n += 256) {
      float s = sbase[(size_t)n * C_];
      if (s > THR && s <= teff) {
        float y1 = bx[(size_t)n * 4 + 0], x1 = bx[(size_t)n * 4 + 1];
        float y2 = bx[(size_t)n * 4 + 2], x2 = bx[(size_t)n * 4 + 3];
        float ar = area_of(y1, x1, y2, x2);
        bool ov = false;
        for (int j = 0; j < nk; ++j) {
          if (iou_gt(ky1[j], kx1[j], ky2[j], kx2[j], kar[j], y1, x1, y2, x2, ar)) { ov = true; break; }
        }
        if (!ov) {
          u64 key = ((u64)__float_as_uint(s) << 32) | (u64)(0xFFFFFFFFu - (unsigned)n);
          best = umax64(best, key);
        }
      }
    }
    red[tid] = best;
    __syncthreads();
    for (int sft = 128; sft > 0; sft >>= 1) {
      if (tid < sft) red[tid] = umax64(red[tid], red[tid + sft]);
      __syncthreads();
    }
    u64 sel = red[0];
    __syncthreads();
    if (sel == 0ull) {
      if (tid == 0) {  // exhausted before MAXK: reference quirk -> keep[anchor 0] = False
        unsigned target = 0xFFFFFFFFu - (unsigned)c;  // anchor 0 -> flat == c
        for (int j = 0; j < nk; ++j)
          if ((unsigned)(kk[j] & 0xFFFFFFFFull) == target) kk[j] = 0ull;
      }
      break;
    }
    unsigned anchor = 0xFFFFFFFFu - (unsigned)(sel & 0xFFFFFFFFull);
    if (tid == 0) {
      float y1 = bx[(size_t)anchor * 4 + 0], x1 = bx[(size_t)anchor * 4 + 1];
      float y2 = bx[(size_t)anchor * 4 + 2], x2 = bx[(size_t)anchor * 4 + 3];
      ky1[nk] = y1; kx1[nk] = x1; ky2[nk] = y2; kx2[nk] = x2; kar[nk] = area_of(y1, x1, y2, x2);
      unsigned flat = anchor * C_ + (unsigned)c;
      kk[nk] = (sel & 0xFFFFFFFF00000000ull) | (u64)(0xFFFFFFFFu - flat);
    }
    ++nk;
    __syncthreads();
  }
  if (tid == 0) nk_arr[gcls] = nk;
}

// ---------- kernel C: 90-way sorted-list merge, one wave per image ----------
#define PRE 32
__global__ __launch_bounds__(64) void merge_kernel(const float* __restrict__ boxes,
                                                   const u64* __restrict__ keepkeys,
                                                   const int* __restrict__ nk_arr,
                                                   float* __restrict__ out) {
  int b = blockIdx.x;
  int lane = threadIdx.x;
  __shared__ u64 pk[C_ * PRE];
  __shared__ u64 selk[MAXK];
  const u64* kk = keepkeys + (size_t)b * C_ * MAXK;

  for (int i = lane; i < C_ * PRE; i += 64) {
    int cc = i / PRE, j = i - cc * PRE;
    pk[i] = kk[(size_t)cc * MAXK + j];
  }
  __syncthreads();

  int c0 = lane, c1 = lane + 64;
  int len0 = (c0 < C_) ? nk_arr[b * C_ + c0] : 0;
  int len1 = (c1 < C_) ? nk_arr[b * C_ + c1] : 0;
  int h0 = 0, h1 = 0;

  auto fetchc = [&](int cc, int& h, int len) -> u64 {
    while (h < len) {
      u64 k = (h < PRE) ? pk[cc * PRE + h] : kk[(size_t)cc * MAXK + h];
      if (k != 0ull) return k;   // skip quirk-nulled holes
      ++h;
    }
    return 0ull;
  };
  u64 cand0 = (c0 < C_) ? fetchc(c0, h0, len0) : 0ull;
  u64 cand1 = (c1 < C_) ? fetchc(c1, h1, len1) : 0ull;

  for (int r = 0; r < MAXK; ++r) {
    u64 my = umax64(cand0, cand1);
    u64 g = my;
#pragma unroll
    for (int m = 1; m < 64; m <<= 1) g = umax64(g, shfl_xor_u64(g, m));
    if (lane == 0) selk[r] = g;
    if (g != 0ull && my == g) {          // unique keys: exactly one owner lane
      if (cand0 == g) { ++h0; cand0 = fetchc(c0, h0, len0); }
      else            { ++h1; cand1 = fetchc(c1, h1, len1); }
    }
  }
  __syncthreads();

  for (int r = lane; r < MAXK; r += 64) {
    u64 s = selk[r];
    float oy1, ox1, oy2, ox2, sc, lb;
    if (s != 0ull) {
      unsigned flat = 0xFFFFFFFFu - (unsigned)(s & 0xFFFFFFFFull);
      unsigned anchor = flat / C_;
      unsigned label = flat - anchor * C_;
      sc = __uint_as_float((unsigned)(s >> 32));
      const float4 bp = ((const float4*)(boxes + (size_t)b * N_ * 4))[anchor];
      oy1 = bp.x; ox1 = bp.y; oy2 = bp.z; ox2 = bp.w;
      lb = (float)label;
    } else {
      oy1 = ox1 = oy2 = ox2 = -1.0f; sc = -1.0f; lb = -1.0f;
    }
    float* bo = out + ((size_t)b * MAXK + r) * 4;
    bo[0] = oy1; bo[1] = ox1; bo[2] = oy2; bo[3] = ox2;
    out[(size_t)B_ * MAXK * 4 + b * MAXK + r] = sc;
    out[(size_t)B_ * MAXK * 4 + B_ * MAXK + b * MAXK + r] = lb;
  }
}

extern "C" void kernel_launch(void* const* d_in, const int* in_sizes, int n_in,
                              void* d_out, int out_size, void* d_ws, size_t ws_size,
                              hipStream_t stream) {
  const float* boxes = (const float*)d_in[0];   // [B,N,4]
  const float* cls = (const float*)d_in[1];     // [B,N,C]
  char* ws = (char*)d_ws;

  u64* keepkeys = (u64*)ws;                       // 360*100*8 = 288000 B
  int* nk_arr   = (int*)(ws + 288000);            // 1440 B
  float* teff_arr = (float*)(ws + 288000 + 1440); // 1440 B
  int* fb_flag  = (int*)(ws + 288000 + 2880);     // 1440 B
  const size_t ts_off = 292352;                   // 256-aligned
  float* ts = (float*)(ws + ts_off);
  size_t need = ts_off + (size_t)B_ * C_ * N_ * sizeof(float);  // ~70.7 MB
  int use_ts = (ws_size >= need) ? 1 : 0;

  if (use_ts)
    transpose_kernel<<<B_ * NTT, 256, 0, stream>>>(cls, ts);
  nms_kernel<<<NCLS, 256, 0, stream>>>(boxes, cls, ts, use_ts,
                                       keepkeys, nk_arr, teff_arr, fb_flag);
  fallback_kernel<<<NCLS, 256, 0, stream>>>(boxes, cls, keepkeys, nk_arr, teff_arr, fb_flag);
  merge_kernel<<<B_, 64, 0, stream>>>(boxes, keepkeys, nk_arr, (float*)d_out);
}

// Round 4
// 298.252 us; speedup vs baseline: 2.8896x; 1.2203x over previous
//
#include <hip/hip_runtime.h>
#include <stdint.h>

typedef unsigned long long u64;

#define B_ 4
#define N_ 49104
#define C_ 90
#define NCLS (B_ * C_)        // 360
#define MAXK 100
#define THR 0.01f
#define CHK 512               // chunk sort size
#define NB2 2048              // fine histogram bins (score_bits[22:12])
#define ACH 512               // anchors per select block
#define NCH ((N_ + ACH - 1) / ACH)   // 96
#define CAPC 72               // per-(class, select-block) LDS list capacity; mean 35.8, +6.2 sigma

// ---------- exact fp32 math matching the numpy/jax reference ----------
__device__ __forceinline__ float area_of(float y1, float x1, float y2, float x2) {
#pragma clang fp contract(off)
  return (y2 - y1) * (x2 - x1);
}

__device__ __forceinline__ bool iou_gt(float ay1, float ax1, float ay2, float ax2, float aa,
                                       float by1, float bx1, float by2, float bx2, float ba) {
#pragma clang fp contract(off)
  float y1 = fmaxf(ay1, by1);
  float x1 = fmaxf(ax1, bx1);
  float y2 = fminf(ay2, by2);
  float x2 = fminf(ax2, bx2);
  float inter = fmaxf(y2 - y1, 0.0f) * fmaxf(x2 - x1, 0.0f);
  float denom = aa + ba - inter + 1e-8f;
  return (inter / denom) > 0.1f;
}

__device__ __forceinline__ u64 umax64(u64 a, u64 b) { return a > b ? a : b; }

__device__ __forceinline__ u64 shfl_xor_u64(u64 v, int m) {
  int lo = __shfl_xor((int)(unsigned)v, m);
  int hi = __shfl_xor((int)(unsigned)(v >> 32), m);
  return ((u64)(unsigned)hi << 32) | (u64)(unsigned)lo;
}

// ---------- kernel S: coalesced slab read -> per-class LDS bins -> bulk global flush ----------
__global__ __launch_bounds__(256) void select_kernel(const float* __restrict__ cls,
                                                     u64* __restrict__ keybuf,
                                                     unsigned* __restrict__ cnt,
                                                     int capsel, float t0) {
  __shared__ u64 ll[C_ * CAPC];        // 51840 B
  __shared__ unsigned lcnt[C_];
  __shared__ unsigned base_s[C_];
  int blk = blockIdx.x;
  int b = blk / NCH, ch = blk - b * NCH;
  int a0 = ch * ACH;
  int aEnd = a0 + ACH; if (aEnd > N_) aEnd = N_;
  int e0 = a0 * C_;                    // image-flat element offset (16B aligned: a0*360B)
  int nelem = (aEnd - a0) * C_;        // divisible by 4 (90*even)
  int tid = threadIdx.x;

  for (int i = tid; i < C_; i += 256) lcnt[i] = 0u;
  __syncthreads();

  const float4* src4 = (const float4*)(cls + (size_t)b * N_ * C_ + e0);
  int n4 = nelem >> 2;
  for (int i4 = tid; i4 < n4; i4 += 256) {
    float4 v = src4[i4];
#pragma unroll
    for (int j = 0; j < 4; ++j) {
      float s = (&v.x)[j];
      if (s > t0) {
        int e = e0 + i4 * 4 + j;
        unsigned n = (unsigned)e / (unsigned)C_;
        unsigned c = (unsigned)e - n * (unsigned)C_;
        u64 key = ((u64)__float_as_uint(s) << 32) | (u64)(0xFFFFFFFFu - n);
        unsigned pos = atomicAdd(&lcnt[c], 1u);
        if (pos < CAPC) {
          ll[c * CAPC + pos] = key;
        } else {                       // LDS list overflow (p ~ 3e-10): exact global spill
          unsigned g = (unsigned)(b * C_) + c;
          unsigned gp = atomicAdd(&cnt[g * 16], 1u);
          if (gp < (unsigned)capsel) keybuf[(size_t)g * capsel + gp] = key;
        }
      }
    }
  }
  __syncthreads();

  if (tid < C_) {
    unsigned cc = lcnt[tid]; if (cc > CAPC) cc = CAPC;
    base_s[tid] = atomicAdd(&cnt[(b * C_ + tid) * 16], cc);
  }
  __syncthreads();

  for (int i = tid; i < C_ * CAPC; i += 256) {
    int c = i / CAPC, j = i - c * CAPC;
    unsigned cc = lcnt[c]; if (cc > CAPC) cc = CAPC;
    if ((unsigned)j < cc) {
      unsigned pos = base_s[c] + (unsigned)j;
      if (pos < (unsigned)capsel)
        keybuf[(size_t)(b * C_ + c) * capsel + pos] = ll[i];
    }
  }
}

// ---------- kernel A: per-class load keys + chunked partial sort + greedy NMS ----------
__global__ __launch_bounds__(256) void nms_kernel(const float* __restrict__ boxes,
                                                  const u64* __restrict__ keybuf,
                                                  const unsigned* __restrict__ cnt,
                                                  int capsel, float t0,
                                                  u64* __restrict__ keepkeys,
                                                  int* __restrict__ nk_arr,
                                                  float* __restrict__ teff_arr,
                                                  int* __restrict__ fb_flag) {
  int gcls = blockIdx.x;
  int b = gcls / C_, c = gcls - b * C_;
  __shared__ u64 karr[4096];           // 32 KB
  __shared__ unsigned hist[NB2];       //  8 KB
  __shared__ u64 ck[CHK];              //  4 KB
  __shared__ float4 ckbox[CHK];        //  8 KB (staged candidate boxes)
  __shared__ int sh_blo, sh_run, sh_nk, sh_cc, sh_over;
  int tid = threadIdx.x;
  int lane = tid & 63;

  for (int i = tid; i < MAXK; i += 256) keepkeys[(size_t)gcls * MAXK + i] = 0ull;

  unsigned Mraw = cnt[gcls * 16];
  if (Mraw > (unsigned)capsel) {       // selection overflow (p < 1e-25): full brute force
    if (tid == 0) { nk_arr[gcls] = 0; teff_arr[gcls] = 2.0f; fb_flag[gcls] = 1; }
    return;
  }
  int M = (int)Mraw;

  for (int i = tid; i < NB2; i += 256) hist[i] = 0u;
  if (tid == 0) { sh_nk = 0; sh_over = 0; }
  __syncthreads();

  const u64* src = keybuf + (size_t)gcls * capsel;
  for (int i = tid; i < M; i += 256) {
    u64 k = src[i];
    karr[i] = k;
    atomicAdd(&hist[(unsigned)(k >> 44) & (NB2 - 1)], 1u);
  }
  __syncthreads();

  // persistent greedy state lives in wave-0 registers across chunk iterations
  float k0y1 = 0, k0x1 = 0, k0y2 = 0, k0x2 = 0, k0a = 0;
  float k1y1 = 0, k1x1 = 0, k1y2 = 0, k1x2 = 0, k1a = 0;
  int nk = 0;
  const float4* bx4 = (const float4*)(boxes + (size_t)b * N_ * 4);

  int bhi = NB2, ext = 0;
  while (ext < M && sh_nk < MAXK) {
    if (tid == 0) {
      int rem = M - ext, run = 0, bb = bhi;
      while (bb > 0) {
        unsigned h = hist[bb - 1];
        if (run + (int)h > CHK) break;
        run += (int)h; --bb;
        if (run >= 480 || run >= rem) break;
      }
      if (run == 0) sh_over = 1;   // single bin > CHK keys (never for uniform scores)
      sh_blo = bb; sh_run = run; sh_cc = 0;
    }
    __syncthreads();
    if (sh_over) break;
    int blo = sh_blo, run = sh_run;

    // compact keys with bin in [blo, bhi)
    for (int i = tid; i < M; i += 256) {
      u64 k = karr[i];
      int bin = (int)((unsigned)(k >> 44) & (NB2 - 1));
      if (bin >= blo && bin < bhi) { int p = atomicAdd(&sh_cc, 1); ck[p] = k; }
    }
    for (int i = run + tid; i < CHK; i += 256) ck[i] = 0ull;
    __syncthreads();

    // bitonic sort CHK keys descending (score desc, anchor asc via ~n packing)
    for (int kk2 = 2; kk2 <= CHK; kk2 <<= 1) {
      for (int j = kk2 >> 1; j > 0; j >>= 1) {
        if (tid < CHK / 2) {
          int i1 = 2 * tid - (tid & (j - 1));
          int i2 = i1 | j;
          u64 a = ck[i1], bb2 = ck[i2];
          bool desc = ((i1 & kk2) == 0);
          bool sw = desc ? (a < bb2) : (a > bb2);
          if (sw) { ck[i1] = bb2; ck[i2] = a; }
        }
        __syncthreads();
      }
    }

    // stage candidate boxes into LDS (coalesced-issue gather, latency overlapped)
    for (int i = tid; i < run; i += 256)
      ckbox[i] = bx4[0xFFFFFFFFu - (unsigned)(ck[i] & 0xFFFFFFFFull)];
    __syncthreads();

    // serial greedy on wave 0; kept boxes distributed across lanes in registers
    if (tid < 64) {
      for (int i = 0; i < run; ++i) {
        u64 key = ck[i];
        unsigned anchor = 0xFFFFFFFFu - (unsigned)(key & 0xFFFFFFFFull);
        float4 cur = ckbox[i];
        float ca = area_of(cur.x, cur.y, cur.z, cur.w);
        bool ov = false;
        if (lane < nk)      ov = iou_gt(k0y1, k0x1, k0y2, k0x2, k0a, cur.x, cur.y, cur.z, cur.w, ca);
        if (lane + 64 < nk) ov = ov || iou_gt(k1y1, k1x1, k1y2, k1x2, k1a, cur.x, cur.y, cur.z, cur.w, ca);
        if (__ballot(ov) == 0ull) {
          if (nk < 64) { if (lane == nk)      { k0y1 = cur.x; k0x1 = cur.y; k0y2 = cur.z; k0x2 = cur.w; k0a = ca; } }
          else         { if (lane == nk - 64) { k1y1 = cur.x; k1x1 = cur.y; k1y2 = cur.z; k1x2 = cur.w; k1a = ca; } }
          if (lane == 0) {
            unsigned flat = anchor * C_ + (unsigned)c;
            keepkeys[(size_t)gcls * MAXK + nk] =
                (key & 0xFFFFFFFF00000000ull) | (u64)(0xFFFFFFFFu - flat);
          }
          ++nk;
          if (nk == MAXK) break;
        }
      }
      if (lane == 0) sh_nk = nk;
    }
    __syncthreads();
    ext += run;
    bhi = blo;
  }

  if (tid == 0) {
    nk_arr[gcls] = nk;
    int fb = 0; float teff = t0;
    if (nk < MAXK) {
      fb = 1;
      if (sh_over)   // remaining keys all below bin bhi; exponent bits = 126
        teff = __uint_as_float(0x3F000000u | (((unsigned)bhi << 12) - 1u));
    }
    fb_flag[gcls] = fb;
    teff_arr[gcls] = teff;
  }
}

// ---------- kernel B: exact brute-force continuation (cold path) ----------
__global__ __launch_bounds__(256) void fallback_kernel(const float* __restrict__ boxes,
                                                       const float* __restrict__ cls,
                                                       u64* __restrict__ keepkeys,
                                                       int* __restrict__ nk_arr,
                                                       float* __restrict__ teff_arr,
                                                       int* __restrict__ fb_flag) {
  int gcls = blockIdx.x;
  if (fb_flag[gcls] == 0) return;
  int b = gcls / C_, c = gcls - b * C_;
  const float* sbase = cls + (size_t)b * N_ * C_ + c;
  float teff = teff_arr[gcls];
  int nk = nk_arr[gcls];
  u64* kk = keepkeys + (size_t)gcls * MAXK;
  const float* bx = boxes + (size_t)b * N_ * 4;

  __shared__ float ky1[MAXK], kx1[MAXK], ky2[MAXK], kx2[MAXK], kar[MAXK];
  __shared__ u64 red[256];
  int tid = threadIdx.x;
  for (int j = tid; j < nk; j += 256) {
    unsigned flat = 0xFFFFFFFFu - (unsigned)(kk[j] & 0xFFFFFFFFull);
    unsigned anchor = flat / C_;
    float y1 = bx[(size_t)anchor * 4 + 0], x1 = bx[(size_t)anchor * 4 + 1];
    float y2 = bx[(size_t)anchor * 4 + 2], x2 = bx[(size_t)anchor * 4 + 3];
    ky1[j] = y1; kx1[j] = x1; ky2[j] = y2; kx2[j] = x2; kar[j] = area_of(y1, x1, y2, x2);
  }
  __syncthreads();

  while (nk < MAXK) {
    u64 best = 0ull;
    for (int n = tid; n < N_; n += 256) {
      float s = sbase[(size_t)n * C_];
      if (s > THR && s <= teff) {
        float y1 = bx[(size_t)n * 4 + 0], x1 = bx[(size_t)n * 4 + 1];
        float y2 = bx[(size_t)n * 4 + 2], x2 = bx[(size_t)n * 4 + 3];
        float ar = area_of(y1, x1, y2, x2);
        bool ov = false;
        for (int j = 0; j < nk; ++j) {
          if (iou_gt(ky1[j], kx1[j], ky2[j], kx2[j], kar[j], y1, x1, y2, x2, ar)) { ov = true; break; }
        }
        if (!ov) {
          u64 key = ((u64)__float_as_uint(s) << 32) | (u64)(0xFFFFFFFFu - (unsigned)n);
          best = umax64(best, key);
        }
      }
    }
    red[tid] = best;
    __syncthreads();
    for (int sft = 128; sft > 0; sft >>= 1) {
      if (tid < sft) red[tid] = umax64(red[tid], red[tid + sft]);
      __syncthreads();
    }
    u64 sel = red[0];
    __syncthreads();
    if (sel == 0ull) {
      if (tid == 0) {  // exhausted before MAXK: reference quirk -> keep[anchor 0] = False
        unsigned target = 0xFFFFFFFFu - (unsigned)c;  // anchor 0 -> flat == c
        for (int j = 0; j < nk; ++j)
          if ((unsigned)(kk[j] & 0xFFFFFFFFull) == target) kk[j] = 0ull;
      }
      break;
    }
    unsigned anchor = 0xFFFFFFFFu - (unsigned)(sel & 0xFFFFFFFFull);
    if (tid == 0) {
      float y1 = bx[(size_t)anchor * 4 + 0], x1 = bx[(size_t)anchor * 4 + 1];
      float y2 = bx[(size_t)anchor * 4 + 2], x2 = bx[(size_t)anchor * 4 + 3];
      ky1[nk] = y1; kx1[nk] = x1; ky2[nk] = y2; kx2[nk] = x2; kar[nk] = area_of(y1, x1, y2, x2);
      unsigned flat = anchor * C_ + (unsigned)c;
      kk[nk] = (sel & 0xFFFFFFFF00000000ull) | (u64)(0xFFFFFFFFu - flat);
    }
    ++nk;
    __syncthreads();
  }
  if (tid == 0) nk_arr[gcls] = nk;
}

// ---------- kernel C: 90-way sorted-list merge, one wave per image ----------
#define PRE 32
__global__ __launch_bounds__(64) void merge_kernel(const float* __restrict__ boxes,
                                                   const u64* __restrict__ keepkeys,
                                                   const int* __restrict__ nk_arr,
                                                   float* __restrict__ out) {
  int b = blockIdx.x;
  int lane = threadIdx.x;
  __shared__ u64 pk[C_ * PRE];
  __shared__ u64 selk[MAXK];
  const u64* kk = keepkeys + (size_t)b * C_ * MAXK;

  for (int i = lane; i < C_ * PRE; i += 64) {
    int cc = i / PRE, j = i - cc * PRE;
    pk[i] = kk[(size_t)cc * MAXK + j];
  }
  __syncthreads();

  int c0 = lane, c1 = lane + 64;
  int len0 = (c0 < C_) ? nk_arr[b * C_ + c0] : 0;
  int len1 = (c1 < C_) ? nk_arr[b * C_ + c1] : 0;
  int h0 = 0, h1 = 0;

  auto fetchc = [&](int cc, int& h, int len) -> u64 {
    while (h < len) {
      u64 k = (h < PRE) ? pk[cc * PRE + h] : kk[(size_t)cc * MAXK + h];
      if (k != 0ull) return k;   // skip quirk-nulled holes
      ++h;
    }
    return 0ull;
  };
  u64 cand0 = (c0 < C_) ? fetchc(c0, h0, len0) : 0ull;
  u64 cand1 = (c1 < C_) ? fetchc(c1, h1, len1) : 0ull;

  for (int r = 0; r < MAXK; ++r) {
    u64 my = umax64(cand0, cand1);
    u64 g = my;
#pragma unroll
    for (int m = 1; m < 64; m <<= 1) g = umax64(g, shfl_xor_u64(g, m));
    if (lane == 0) selk[r] = g;
    if (g != 0ull && my == g) {          // unique keys: exactly one owner lane
      if (cand0 == g) { ++h0; cand0 = fetchc(c0, h0, len0); }
      else            { ++h1; cand1 = fetchc(c1, h1, len1); }
    }
  }
  __syncthreads();

  for (int r = lane; r < MAXK; r += 64) {
    u64 s = selk[r];
    float oy1, ox1, oy2, ox2, sc, lb;
    if (s != 0ull) {
      unsigned flat = 0xFFFFFFFFu - (unsigned)(s & 0xFFFFFFFFull);
      unsigned anchor = flat / C_;
      unsigned label = flat - anchor * C_;
      sc = __uint_as_float((unsigned)(s >> 32));
      const float4 bp = ((const float4*)(boxes + (size_t)b * N_ * 4))[anchor];
      oy1 = bp.x; ox1 = bp.y; oy2 = bp.z; ox2 = bp.w;
      lb = (float)label;
    } else {
      oy1 = ox1 = oy2 = ox2 = -1.0f; sc = -1.0f; lb = -1.0f;
    }
    float* bo = out + ((size_t)b * MAXK + r) * 4;
    bo[0] = oy1; bo[1] = ox1; bo[2] = oy2; bo[3] = ox2;
    out[(size_t)B_ * MAXK * 4 + b * MAXK + r] = sc;
    out[(size_t)B_ * MAXK * 4 + B_ * MAXK + b * MAXK + r] = lb;
  }
}

extern "C" void kernel_launch(void* const* d_in, const int* in_sizes, int n_in,
                              void* d_out, int out_size, void* d_ws, size_t ws_size,
                              hipStream_t stream) {
  const float* boxes = (const float*)d_in[0];   // [B,N,4]
  const float* cls = (const float*)d_in[1];     // [B,N,C]
  char* ws = (char*)d_ws;

  // capacity/threshold tiers by available workspace
  int capsel; float t0;
  auto need_for = [](int cap) -> size_t {
    return 23040 + (size_t)NCLS * cap * 8 + 288000 + 3 * 1440;
  };
  if (ws_size >= need_for(4096))      { capsel = 4096; t0 = 0.93f;  }  // M ~ 3437 +/- 57
  else if (ws_size >= need_for(2048)) { capsel = 2048; t0 = 0.962f; }  // M ~ 1866 +/- 42
  else                                { capsel = 1024; t0 = 0.985f; }  // M ~  737 +/- 27

  unsigned* cnt = (unsigned*)ws;                      // 360 counters, 64B padded
  u64* keybuf = (u64*)(ws + 23040);
  size_t off = 23040 + (size_t)NCLS * capsel * 8;
  u64* keepkeys = (u64*)(ws + off);      off += 288000;
  int* nk_arr = (int*)(ws + off);        off += 1440;
  float* teff_arr = (float*)(ws + off);  off += 1440;
  int* fb_flag = (int*)(ws + off);

  hipMemsetAsync(cnt, 0, 23040, stream);
  select_kernel<<<B_ * NCH, 256, 0, stream>>>(cls, keybuf, cnt, capsel, t0);
  nms_kernel<<<NCLS, 256, 0, stream>>>(boxes, keybuf, cnt, capsel, t0,
                                       keepkeys, nk_arr, teff_arr, fb_flag);
  fallback_kernel<<<NCLS, 256, 0, stream>>>(boxes, cls, keepkeys, nk_arr, teff_arr, fb_flag);
  merge_kernel<<<B_, 64, 0, stream>>>(boxes, keepkeys, nk_arr, (float*)d_out);
}

// Round 5
// 266.075 us; speedup vs baseline: 3.2391x; 1.1209x over previous
//
#include <hip/hip_runtime.h>
#include <stdint.h>

typedef unsigned long long u64;

#define B_ 4
#define N_ 49104
#define C_ 90
#define NCLS (B_ * C_)        // 360
#define MAXK 100
#define THR 0.01f
#define CHK 512               // chunk sort size
#define NB2 2048              // fine histogram bins (score_bits[22:12])
#define ACH 512               // anchors per select block
#define NCH ((N_ + ACH - 1) / ACH)   // 96
#define CAPC 72               // per-(class, select-block) LDS list capacity; mean 35.8, +6.2 sigma

// ---------- exact fp32 math matching the numpy/jax reference ----------
__device__ __forceinline__ float area_of(float y1, float x1, float y2, float x2) {
#pragma clang fp contract(off)
  return (y2 - y1) * (x2 - x1);
}

// denom = aa + ba - inter + 1e-8 with aa = SELECTED box area (reference arg order)
__device__ __forceinline__ bool iou_gt(float ay1, float ax1, float ay2, float ax2, float aa,
                                       float by1, float bx1, float by2, float bx2, float ba) {
#pragma clang fp contract(off)
  float y1 = fmaxf(ay1, by1);
  float x1 = fmaxf(ax1, bx1);
  float y2 = fminf(ay2, by2);
  float x2 = fminf(ax2, bx2);
  float inter = fmaxf(y2 - y1, 0.0f) * fmaxf(x2 - x1, 0.0f);
  float denom = aa + ba - inter + 1e-8f;
  return (inter / denom) > 0.1f;
}

__device__ __forceinline__ u64 umax64(u64 a, u64 b) { return a > b ? a : b; }

__device__ __forceinline__ u64 shfl_xor_u64(u64 v, int m) {
  int lo = __shfl_xor((int)(unsigned)v, m);
  int hi = __shfl_xor((int)(unsigned)(v >> 32), m);
  return ((u64)(unsigned)hi << 32) | (u64)(unsigned)lo;
}

// ---------- kernel S: coalesced slab read -> per-class LDS bins -> bulk global flush ----------
__global__ __launch_bounds__(256) void select_kernel(const float* __restrict__ cls,
                                                     u64* __restrict__ keybuf,
                                                     unsigned* __restrict__ cnt,
                                                     int capsel, float t0) {
  __shared__ u64 ll[C_ * CAPC];        // 51840 B
  __shared__ unsigned lcnt[C_];
  __shared__ unsigned base_s[C_];
  int blk = blockIdx.x;
  int b = blk / NCH, ch = blk - b * NCH;
  int a0 = ch * ACH;
  int aEnd = a0 + ACH; if (aEnd > N_) aEnd = N_;
  int e0 = a0 * C_;
  int nelem = (aEnd - a0) * C_;
  int tid = threadIdx.x;

  for (int i = tid; i < C_; i += 256) lcnt[i] = 0u;
  __syncthreads();

  const float4* src4 = (const float4*)(cls + (size_t)b * N_ * C_ + e0);
  int n4 = nelem >> 2;
  for (int i4 = tid; i4 < n4; i4 += 256) {
    float4 v = src4[i4];
#pragma unroll
    for (int j = 0; j < 4; ++j) {
      float s = (&v.x)[j];
      if (s > t0) {
        int e = e0 + i4 * 4 + j;
        unsigned n = (unsigned)e / (unsigned)C_;
        unsigned c = (unsigned)e - n * (unsigned)C_;
        u64 key = ((u64)__float_as_uint(s) << 32) | (u64)(0xFFFFFFFFu - n);
        unsigned pos = atomicAdd(&lcnt[c], 1u);
        if (pos < CAPC) {
          ll[c * CAPC + pos] = key;
        } else {                       // LDS list overflow (p ~ 3e-10): exact global spill
          unsigned g = (unsigned)(b * C_) + c;
          unsigned gp = atomicAdd(&cnt[g * 16], 1u);
          if (gp < (unsigned)capsel) keybuf[(size_t)g * capsel + gp] = key;
        }
      }
    }
  }
  __syncthreads();

  if (tid < C_) {
    unsigned cc = lcnt[tid]; if (cc > CAPC) cc = CAPC;
    base_s[tid] = atomicAdd(&cnt[(b * C_ + tid) * 16], cc);
  }
  __syncthreads();

  for (int i = tid; i < C_ * CAPC; i += 256) {
    int c = i / CAPC, j = i - c * CAPC;
    unsigned cc = lcnt[c]; if (cc > CAPC) cc = CAPC;
    if ((unsigned)j < cc) {
      unsigned pos = base_s[c] + (unsigned)j;
      if (pos < (unsigned)capsel)
        keybuf[(size_t)(b * C_ + c) * capsel + pos] = ll[i];
    }
  }
}

// ---------- kernel A: load keys + chunked sort + bitmask greedy + inline exact fallback ----------
__global__ __launch_bounds__(256) void nms_kernel(const float* __restrict__ boxes,
                                                  const float* __restrict__ cls,
                                                  const u64* __restrict__ keybuf,
                                                  const unsigned* __restrict__ cnt,
                                                  int capsel, float t0,
                                                  u64* __restrict__ keepkeys,
                                                  int* __restrict__ nk_arr) {
  int gcls = blockIdx.x;
  int b = gcls / C_, c = gcls - b * C_;
  __shared__ u64 karr[4096];           // 32 KB raw keys
  __shared__ unsigned hist[NB2];       //  8 KB
  __shared__ u64 ck[CHK];              //  4 KB sorted chunk
  __shared__ float4 ckbox[CHK];        //  8 KB candidate boxes
  __shared__ float carea[CHK];         //  2 KB candidate areas
  __shared__ float4 kb[MAXK];          //  kept boxes (cross-chunk / fallback)
  __shared__ float ka[MAXK];           //  kept areas
  __shared__ u64 red[256];             //  2 KB fallback reduction
  __shared__ int sh_blo, sh_run, sh_nk, sh_cc, sh_over;
  int tid = threadIdx.x;
  int lane = tid & 63;

  for (int i = tid; i < MAXK; i += 256) keepkeys[(size_t)gcls * MAXK + i] = 0ull;
  for (int i = tid; i < NB2; i += 256) hist[i] = 0u;
  if (tid == 0) { sh_nk = 0; sh_over = 0; }
  __syncthreads();

  unsigned Mraw = cnt[gcls * 16];
  bool overflow = (Mraw > (unsigned)capsel);   // p < 1e-25: full brute force below
  int M = overflow ? 0 : (int)Mraw;

  const u64* src = keybuf + (size_t)gcls * capsel;
  for (int i = tid; i < M; i += 256) {
    u64 k = src[i];
    karr[i] = k;
    atomicAdd(&hist[(unsigned)(k >> 44) & (NB2 - 1)], 1u);
  }
  __syncthreads();

  const float4* bx4 = (const float4*)(boxes + (size_t)b * N_ * 4);
  int nk = 0;                          // authoritative in wave 0 during chunk loop
  int bhi = NB2, ext = 0;

  while (ext < M && sh_nk < MAXK) {
    if (tid == 0) {
      int rem = M - ext, run = 0, bb = bhi;
      while (bb > 0) {
        unsigned h = hist[bb - 1];
        if (run + (int)h > CHK) break;
        run += (int)h; --bb;
        if (run >= 480 || run >= rem) break;
      }
      if (run == 0) sh_over = 1;   // single bin > CHK keys (never for uniform scores)
      sh_blo = bb; sh_run = run; sh_cc = 0;
    }
    __syncthreads();
    if (sh_over) break;
    int blo = sh_blo, run = sh_run;

    // compact keys with bin in [blo, bhi)
    for (int i = tid; i < M; i += 256) {
      u64 k = karr[i];
      int bin = (int)((unsigned)(k >> 44) & (NB2 - 1));
      if (bin >= blo && bin < bhi) { int p = atomicAdd(&sh_cc, 1); ck[p] = k; }
    }
    for (int i = run + tid; i < CHK; i += 256) ck[i] = 0ull;
    __syncthreads();

    // bitonic sort CHK keys descending (score desc, anchor asc via ~n packing)
    for (int kk2 = 2; kk2 <= CHK; kk2 <<= 1) {
      for (int j = kk2 >> 1; j > 0; j >>= 1) {
        if (tid < CHK / 2) {
          int i1 = 2 * tid - (tid & (j - 1));
          int i2 = i1 | j;
          u64 a = ck[i1], bb2 = ck[i2];
          bool desc = ((i1 & kk2) == 0);
          bool sw = desc ? (a < bb2) : (a > bb2);
          if (sw) { ck[i1] = bb2; ck[i2] = a; }
        }
        __syncthreads();
      }
    }

    // stage candidate boxes + areas into LDS
    for (int i = tid; i < run; i += 256) {
      float4 bxv = bx4[0xFFFFFFFFu - (unsigned)(ck[i] & 0xFFFFFFFFull)];
      ckbox[i] = bxv;
      carea[i] = area_of(bxv.x, bxv.y, bxv.z, bxv.w);
    }
    for (int i = run + tid; i < CHK; i += 256) {
      ckbox[i] = make_float4(0.f, 0.f, 0.f, 0.f);
      carea[i] = 0.f;
    }
    __syncthreads();

    // bitmask greedy on wave 0: pop lowest alive bit == next keep (exact greedy order);
    // each keep does one wave-parallel suppress (8 IOU sets -> 8 ballots)
    if (tid < 64) {
      float4 cb_[8]; float ca_[8];
#pragma unroll
      for (int s = 0; s < 8; ++s) { cb_[s] = ckbox[s * 64 + lane]; ca_[s] = carea[s * 64 + lane]; }
      u64 alive[8];
#pragma unroll
      for (int s = 0; s < 8; ++s) {
        int lo = s * 64;
        alive[s] = (run >= lo + 64) ? ~0ull
                 : (run > lo ? ((1ull << (run - lo)) - 1ull) : 0ull);
      }
      // suppress by keeps from previous chunks (rare: only when ext > 0)
      for (int j = 0; j < nk; ++j) {
        float4 sb = kb[j]; float sa = ka[j];
#pragma unroll
        for (int s = 0; s < 8; ++s)
          alive[s] &= ~__ballot(iou_gt(sb.x, sb.y, sb.z, sb.w, sa,
                                       cb_[s].x, cb_[s].y, cb_[s].z, cb_[s].w, ca_[s]));
      }
#pragma unroll 1
      for (int w = 0; w < 8; ++w) {
        while (alive[w] != 0ull && nk < MAXK) {
          int bit = __ffsll((long long)alive[w]) - 1;
          int i = w * 64 + bit;
          float4 sb = ckbox[i];        // wave-uniform broadcast reads
          float sa = carea[i];
          u64 key = ck[i];
          if (lane == 0) {
            unsigned anchor = 0xFFFFFFFFu - (unsigned)(key & 0xFFFFFFFFull);
            unsigned flat = anchor * C_ + (unsigned)c;
            keepkeys[(size_t)gcls * MAXK + nk] =
                (key & 0xFFFFFFFF00000000ull) | (u64)(0xFFFFFFFFu - flat);
            kb[nk] = sb; ka[nk] = sa;
          }
          ++nk;
#pragma unroll
          for (int s = 0; s < 8; ++s)
            alive[s] &= ~__ballot(iou_gt(sb.x, sb.y, sb.z, sb.w, sa,
                                         cb_[s].x, cb_[s].y, cb_[s].z, cb_[s].w, ca_[s]));
          // self-bit always cleared (self-IOU ~ 1 > 0.1); lower bits already processed
        }
        if (nk >= MAXK) break;
      }
      if (lane == 0) sh_nk = nk;
    }
    __syncthreads();
    ext += run;
    bhi = blo;
  }

  // ---- inline exact continuation (cold path) ----
  int nkF = sh_nk;
  if (nkF < MAXK) {
    float teff;
    if (overflow)     teff = 2.0f;
    else if (sh_over) teff = __uint_as_float(0x3F000000u | (((unsigned)bhi << 12) - 1u));
    else              teff = t0;
    const float* sbase = cls + (size_t)b * N_ * C_ + c;
    const float* bx = boxes + (size_t)b * N_ * 4;
    u64* kkp = keepkeys + (size_t)gcls * MAXK;
    int nk2 = nkF;
    while (nk2 < MAXK) {
      u64 best = 0ull;
      for (int n = tid; n < N_; n += 256) {
        float s = sbase[(size_t)n * C_];
        if (s > THR && s <= teff) {
          float y1 = bx[(size_t)n * 4 + 0], x1 = bx[(size_t)n * 4 + 1];
          float y2 = bx[(size_t)n * 4 + 2], x2 = bx[(size_t)n * 4 + 3];
          float ar = area_of(y1, x1, y2, x2);
          bool ov = false;
          for (int j = 0; j < nk2; ++j) {
            float4 kbj = kb[j];
            if (iou_gt(kbj.x, kbj.y, kbj.z, kbj.w, ka[j], y1, x1, y2, x2, ar)) { ov = true; break; }
          }
          if (!ov) {
            u64 key = ((u64)__float_as_uint(s) << 32) | (u64)(0xFFFFFFFFu - (unsigned)n);
            best = umax64(best, key);
          }
        }
      }
      red[tid] = best;
      __syncthreads();
      for (int sft = 128; sft > 0; sft >>= 1) {
        if (tid < sft) red[tid] = umax64(red[tid], red[tid + sft]);
        __syncthreads();
      }
      u64 sel = red[0];
      __syncthreads();
      if (sel == 0ull) {
        if (tid == 0) {  // exhausted before MAXK: reference quirk -> keep[anchor 0] = False
          unsigned target = 0xFFFFFFFFu - (unsigned)c;  // anchor 0 -> flat == c
          for (int j = 0; j < nk2; ++j)
            if ((unsigned)(kkp[j] & 0xFFFFFFFFull) == target) kkp[j] = 0ull;
        }
        break;
      }
      unsigned anchor = 0xFFFFFFFFu - (unsigned)(sel & 0xFFFFFFFFull);
      if (tid == 0) {
        float y1 = bx[(size_t)anchor * 4 + 0], x1 = bx[(size_t)anchor * 4 + 1];
        float y2 = bx[(size_t)anchor * 4 + 2], x2 = bx[(size_t)anchor * 4 + 3];
        kb[nk2] = make_float4(y1, x1, y2, x2);
        ka[nk2] = area_of(y1, x1, y2, x2);
        unsigned flat = anchor * C_ + (unsigned)c;
        kkp[nk2] = (sel & 0xFFFFFFFF00000000ull) | (u64)(0xFFFFFFFFu - flat);
      }
      ++nk2;
      __syncthreads();
    }
    nkF = nk2;
  }
  if (tid == 0) nk_arr[gcls] = nkF;
}

// ---------- kernel C: 90-way sorted-list merge, one wave per image ----------
#define PRE 32
__global__ __launch_bounds__(64) void merge_kernel(const float* __restrict__ boxes,
                                                   const u64* __restrict__ keepkeys,
                                                   const int* __restrict__ nk_arr,
                                                   float* __restrict__ out) {
  int b = blockIdx.x;
  int lane = threadIdx.x;
  __shared__ u64 pk[C_ * PRE];
  __shared__ u64 selk[MAXK];
  const u64* kk = keepkeys + (size_t)b * C_ * MAXK;

  for (int i = lane; i < C_ * PRE; i += 64) {
    int cc = i / PRE, j = i - cc * PRE;
    pk[i] = kk[(size_t)cc * MAXK + j];
  }
  __syncthreads();

  int c0 = lane, c1 = lane + 64;
  int len0 = (c0 < C_) ? nk_arr[b * C_ + c0] : 0;
  int len1 = (c1 < C_) ? nk_arr[b * C_ + c1] : 0;
  int h0 = 0, h1 = 0;

  auto fetchc = [&](int cc, int& h, int len) -> u64 {
    while (h < len) {
      u64 k = (h < PRE) ? pk[cc * PRE + h] : kk[(size_t)cc * MAXK + h];
      if (k != 0ull) return k;   // skip quirk-nulled holes
      ++h;
    }
    return 0ull;
  };
  u64 cand0 = (c0 < C_) ? fetchc(c0, h0, len0) : 0ull;
  u64 cand1 = (c1 < C_) ? fetchc(c1, h1, len1) : 0ull;

  for (int r = 0; r < MAXK; ++r) {
    u64 my = umax64(cand0, cand1);
    u64 g = my;
#pragma unroll
    for (int m = 1; m < 64; m <<= 1) g = umax64(g, shfl_xor_u64(g, m));
    if (lane == 0) selk[r] = g;
    if (g != 0ull && my == g) {          // unique keys: exactly one owner lane
      if (cand0 == g) { ++h0; cand0 = fetchc(c0, h0, len0); }
      else            { ++h1; cand1 = fetchc(c1, h1, len1); }
    }
  }
  __syncthreads();

  for (int r = lane; r < MAXK; r += 64) {
    u64 s = selk[r];
    float oy1, ox1, oy2, ox2, sc, lb;
    if (s != 0ull) {
      unsigned flat = 0xFFFFFFFFu - (unsigned)(s & 0xFFFFFFFFull);
      unsigned anchor = flat / C_;
      unsigned label = flat - anchor * C_;
      sc = __uint_as_float((unsigned)(s >> 32));
      const float4 bp = ((const float4*)(boxes + (size_t)b * N_ * 4))[anchor];
      oy1 = bp.x; ox1 = bp.y; oy2 = bp.z; ox2 = bp.w;
      lb = (float)label;
    } else {
      oy1 = ox1 = oy2 = ox2 = -1.0f; sc = -1.0f; lb = -1.0f;
    }
    float* bo = out + ((size_t)b * MAXK + r) * 4;
    bo[0] = oy1; bo[1] = ox1; bo[2] = oy2; bo[3] = ox2;
    out[(size_t)B_ * MAXK * 4 + b * MAXK + r] = sc;
    out[(size_t)B_ * MAXK * 4 + B_ * MAXK + b * MAXK + r] = lb;
  }
}

extern "C" void kernel_launch(void* const* d_in, const int* in_sizes, int n_in,
                              void* d_out, int out_size, void* d_ws, size_t ws_size,
                              hipStream_t stream) {
  const float* boxes = (const float*)d_in[0];   // [B,N,4]
  const float* cls = (const float*)d_in[1];     // [B,N,C]
  char* ws = (char*)d_ws;

  // capacity/threshold tiers by available workspace
  int capsel; float t0;
  auto need_for = [](int cap) -> size_t {
    return 23040 + (size_t)NCLS * cap * 8 + 288000 + 1440;
  };
  if (ws_size >= need_for(4096))      { capsel = 4096; t0 = 0.93f;  }  // M ~ 3437 +/- 57
  else if (ws_size >= need_for(2048)) { capsel = 2048; t0 = 0.962f; }  // M ~ 1866 +/- 42
  else                                { capsel = 1024; t0 = 0.985f; }  // M ~  737 +/- 27

  unsigned* cnt = (unsigned*)ws;                      // 360 counters, 64B padded
  u64* keybuf = (u64*)(ws + 23040);
  size_t off = 23040 + (size_t)NCLS * capsel * 8;
  u64* keepkeys = (u64*)(ws + off);      off += 288000;
  int* nk_arr = (int*)(ws + off);

  hipMemsetAsync(cnt, 0, 23040, stream);
  select_kernel<<<B_ * NCH, 256, 0, stream>>>(cls, keybuf, cnt, capsel, t0);
  nms_kernel<<<NCLS, 256, 0, stream>>>(boxes, cls, keybuf, cnt, capsel, t0,
                                       keepkeys, nk_arr);
  merge_kernel<<<B_, 64, 0, stream>>>(boxes, keepkeys, nk_arr, (float*)d_out);
}

// Round 6
// 222.517 us; speedup vs baseline: 3.8731x; 1.1958x over previous
//
#include <hip/hip_runtime.h>
#include <stdint.h>

typedef unsigned long long u64;

#define B_ 4
#define N_ 49104
#define C_ 90
#define NCLS (B_ * C_)        // 360
#define MAXK 100
#define THR 0.01f
#define CHKB 1024             // greedy window capacity
#define NBIN 2304             // fine bins over scores in (0.9296875, 1.0)
#define BINBASE 0x3F6E0000u   // float bits 0.9296875 (valid for all t0 tiers >= 0.93)
#define BINSH 9
#define ACH 256               // anchors per select block
#define NCH ((N_ + ACH - 1) / ACH)   // 192
#define CAPC 48               // per-(class, select-block) LDS capacity; mean 17.9, +7.4 sigma

// ---------- exact fp32 math matching the numpy/jax reference ----------
__device__ __forceinline__ float area_of(float y1, float x1, float y2, float x2) {
#pragma clang fp contract(off)
  return (y2 - y1) * (x2 - x1);
}

// aa = SELECTED (kept) box area, ba = candidate area (reference arg order)
__device__ __forceinline__ bool iou_gt(float ay1, float ax1, float ay2, float ax2, float aa,
                                       float by1, float bx1, float by2, float bx2, float ba) {
#pragma clang fp contract(off)
  float y1 = fmaxf(ay1, by1);
  float x1 = fmaxf(ax1, bx1);
  float y2 = fminf(ay2, by2);
  float x2 = fminf(ax2, bx2);
  float inter = fmaxf(y2 - y1, 0.0f) * fmaxf(x2 - x1, 0.0f);
  float denom = aa + ba - inter + 1e-8f;
  return (inter / denom) > 0.1f;
}

__device__ __forceinline__ u64 umax64(u64 a, u64 b) { return a > b ? a : b; }

__device__ __forceinline__ u64 shfl_xor_u64(u64 v, int m) {
  int lo = __shfl_xor((int)(unsigned)v, m);
  int hi = __shfl_xor((int)(unsigned)(v >> 32), m);
  return ((u64)(unsigned)hi << 32) | (u64)(unsigned)lo;
}

__device__ __forceinline__ int key2bin(u64 k) {
  int d = (int)((unsigned)(k >> 32) - BINBASE);
  int bin = d >> BINSH;
  if (d < 0) bin = 0;
  if (bin > NBIN - 1) bin = NBIN - 1;
  return bin;
}

// ---------- kernel S: coalesced slab read -> per-class LDS bins -> bulk global flush ----------
__global__ __launch_bounds__(256) void select_kernel(const float* __restrict__ cls,
                                                     u64* __restrict__ keybuf,
                                                     unsigned* __restrict__ cnt,
                                                     int capsel, float t0) {
  __shared__ u64 ll[C_ * CAPC];        // 34560 B
  __shared__ unsigned lcnt[C_];
  __shared__ unsigned base_s[C_];
  int blk = blockIdx.x;
  int b = blk / NCH, ch = blk - b * NCH;
  int a0 = ch * ACH;
  int aEnd = a0 + ACH; if (aEnd > N_) aEnd = N_;
  int e0 = a0 * C_;                    // 16B-aligned (a0*360B)
  int nelem = (aEnd - a0) * C_;
  int tid = threadIdx.x;

  for (int i = tid; i < C_; i += 256) lcnt[i] = 0u;
  __syncthreads();

  const float4* src4 = (const float4*)(cls + (size_t)b * N_ * C_ + e0);
  int n4 = nelem >> 2;
  auto proc = [&](float s, int e) {
    if (s > t0) {
      unsigned n = (unsigned)e / (unsigned)C_;
      unsigned c = (unsigned)e - n * (unsigned)C_;
      u64 key = ((u64)__float_as_uint(s) << 32) | (u64)(0xFFFFFFFFu - n);
      unsigned pos = atomicAdd(&lcnt[c], 1u);
      if (pos < CAPC) {
        ll[c * CAPC + pos] = key;
      } else {                         // LDS overflow (p ~ 1e-13): exact global spill
        unsigned g = (unsigned)(b * C_) + c;
        unsigned gp = atomicAdd(&cnt[g * 16], 1u);
        if (gp < (unsigned)capsel) keybuf[(size_t)g * capsel + gp] = key;
      }
    }
  };
  // batch 4 strided float4 loads for ILP (BW-bound, not latency-bound)
  for (int i4 = tid; i4 < n4; i4 += 1024) {
    float4 v0, v1, v2, v3;
    int g1 = i4 + 256, g2 = i4 + 512, g3 = i4 + 768;
    v0 = src4[i4];
    if (g1 < n4) v1 = src4[g1];
    if (g2 < n4) v2 = src4[g2];
    if (g3 < n4) v3 = src4[g3];
#pragma unroll
    for (int j = 0; j < 4; ++j) proc((&v0.x)[j], e0 + i4 * 4 + j);
    if (g1 < n4) {
#pragma unroll
      for (int j = 0; j < 4; ++j) proc((&v1.x)[j], e0 + g1 * 4 + j);
    }
    if (g2 < n4) {
#pragma unroll
      for (int j = 0; j < 4; ++j) proc((&v2.x)[j], e0 + g2 * 4 + j);
    }
    if (g3 < n4) {
#pragma unroll
      for (int j = 0; j < 4; ++j) proc((&v3.x)[j], e0 + g3 * 4 + j);
    }
  }
  __syncthreads();

  if (tid < C_) {
    unsigned cc = lcnt[tid]; if (cc > CAPC) cc = CAPC;
    base_s[tid] = atomicAdd(&cnt[(b * C_ + tid) * 16], cc);
  }
  __syncthreads();

  for (int i = tid; i < C_ * CAPC; i += 256) {
    int c = i / CAPC, j = i - c * CAPC;
    unsigned cc = lcnt[c]; if (cc > CAPC) cc = CAPC;
    if ((unsigned)j < cc) {
      unsigned pos = base_s[c] + (unsigned)j;
      if (pos < (unsigned)capsel)
        keybuf[(size_t)(b * C_ + c) * capsel + pos] = ll[i];
    }
  }
}

// ---------- kernel A: counting-rank sort + frontier greedy + inline exact fallback ----------
__global__ __launch_bounds__(256) void nms_kernel(const float* __restrict__ boxes,
                                                  const float* __restrict__ cls,
                                                  const u64* __restrict__ keybuf,
                                                  const unsigned* __restrict__ cnt,
                                                  int capsel, float t0,
                                                  u64* __restrict__ keepkeys,
                                                  int* __restrict__ nk_arr) {
  int gcls = blockIdx.x;
  int b = gcls / C_, c = gcls - b * C_;
  __shared__ unsigned hist[NBIN];      //  9 KB
  __shared__ unsigned rb[NBIN];        //  9 KB (rank base / scatter cursor)
  __shared__ u64 ck[CHKB];             //  8 KB sorted window
  __shared__ float4 ckbox[CHKB];       // 16 KB candidate boxes
  __shared__ float carea[CHKB];        //  4 KB candidate areas
  __shared__ float4 kb[MAXK];          //  kept boxes
  __shared__ float ka[MAXK];           //  kept areas
  __shared__ u64 red[256];             //  2 KB fallback reduction
  __shared__ unsigned wsum[4];
  __shared__ int sh_blo, sh_run, sh_nk, sh_over;
  int tid = threadIdx.x;
  int lane = tid & 63;
  int wid = tid >> 6;

  for (int i = tid; i < MAXK; i += 256) keepkeys[(size_t)gcls * MAXK + i] = 0ull;
  for (int i = tid; i < NBIN; i += 256) hist[i] = 0u;
  if (tid == 0) { sh_nk = 0; sh_over = 0; }
  __syncthreads();

  unsigned Mraw = cnt[gcls * 16];
  bool overflow = (Mraw > (unsigned)capsel);   // p < 1e-25: full brute force below
  int M = overflow ? 0 : (int)Mraw;

  const u64* src = keybuf + (size_t)gcls * capsel;
  for (int i = tid; i < M; i += 256) atomicAdd(&hist[key2bin(src[i])], 1u);
  __syncthreads();

  const float4* bx4 = (const float4*)(boxes + (size_t)b * N_ * 4);
  int nk = 0;                          // authoritative in wave 0
  int bhi = NBIN, ext = 0;
  const int W = 9;                     // NBIN / 256

  while (ext < M && sh_nk < MAXK) {
    if (tid == 0) sh_blo = bhi;
    __syncthreads();

    // parallel suffix ranks over reversed stripes: rank_base[bin] = #keys in bins > bin (< bhi)
    int j0 = tid * W;
    unsigned psum = 0;
#pragma unroll
    for (int q = 0; q < W; ++q) {
      int bin = bhi - 1 - (j0 + q);
      if (bin >= 0) psum += hist[bin];
    }
    unsigned incl = psum;
#pragma unroll
    for (int s = 1; s < 64; s <<= 1) {
      unsigned v = (unsigned)__shfl_up((int)incl, s);
      if (lane >= s) incl += v;
    }
    if (lane == 63) wsum[wid] = incl;
    __syncthreads();
    unsigned base = 0;
    for (int w2 = 0; w2 < wid; ++w2) base += wsum[w2];
    unsigned running = base + incl - psum;
    int myblo = bhi;
#pragma unroll
    for (int q = 0; q < W; ++q) {
      int bin = bhi - 1 - (j0 + q);
      if (bin >= 0) {
        rb[bin] = running;
        running += hist[bin];
        if (running <= CHKB) myblo = bin;   // S[bin] <= CHKB qualifies; walk ends at smallest
      }
    }
    if (myblo < bhi) atomicMin(&sh_blo, myblo);
    __syncthreads();
    if (tid == 0) {
      int blo = sh_blo;
      int run = (blo < bhi) ? (int)(rb[blo] + hist[blo]) : 0;
      if (run == 0) sh_over = 1;       // a single bin > CHKB keys (never for uniform scores)
      sh_run = run;
    }
    __syncthreads();
    if (sh_over) break;
    int blo = sh_blo, run = sh_run;

    // scatter into exact descending rank positions (intra-bin order fixed below)
    for (int i = tid; i < M; i += 256) {
      u64 k = src[i];
      int bin = key2bin(k);
      if (bin >= blo && bin < bhi) {
        unsigned pos = atomicAdd(&rb[bin], 1u);
        ck[pos] = k;
      }
    }
    __syncthreads();
    // intra-bin fixup: insertion-sort each bin run descending by full key (exact ties)
    int wlen = bhi - blo;
    for (int idx = tid; idx < wlen; idx += 256) {
      int bin = blo + idx;
      unsigned h2 = hist[bin];
      if (h2 >= 2u) {
        unsigned end = rb[bin];        // = start + h2 after scatter
        unsigned st = end - h2;
        for (unsigned a = st + 1; a < end; ++a) {
          u64 kv = ck[a]; unsigned p2 = a;
          while (p2 > st && ck[p2 - 1] < kv) { ck[p2] = ck[p2 - 1]; --p2; }
          ck[p2] = kv;
        }
      }
    }
    __syncthreads();
    // stage candidate boxes + areas
    for (int i = tid; i < run; i += 256) {
      float4 v = bx4[0xFFFFFFFFu - (unsigned)(ck[i] & 0xFFFFFFFFull)];
      ckbox[i] = v;
      carea[i] = area_of(v.x, v.y, v.z, v.w);
    }
    __syncthreads();

    // frontier greedy on wave 0: lane owns ONE candidate of the current 64-word;
    // catch-up vs keeps at word entry; per keep suppress only the current word.
    if (wid == 0) {
      int nwords = (run + 63) >> 6;
      for (int w = 0; w < nwords; ++w) {
        int ibase = w << 6;
        int myi = ibase + lane;
        float4 mb = make_float4(-1e30f, -1e30f, -1e30f, -1e30f);
        float ma = 0.f;
        if (myi < run) { mb = ckbox[myi]; ma = carea[myi]; }
        int remw = run - ibase;
        u64 alive = (remw >= 64) ? ~0ull : ((1ull << remw) - 1ull);
        for (int j = 0; j < nk; ++j) {  // catch-up (covers earlier words AND earlier chunks)
          float4 sb = kb[j]; float sa = ka[j];
          alive &= ~__ballot(iou_gt(sb.x, sb.y, sb.z, sb.w, sa, mb.x, mb.y, mb.z, mb.w, ma));
        }
        while (alive != 0ull) {
          int bit = __ffsll((long long)alive) - 1;
          int ii = ibase + bit;
          float4 sb = ckbox[ii];        // wave-uniform broadcast
          float sa = carea[ii];
          u64 key = ck[ii];
          if (lane == 0) {
            unsigned anchor = 0xFFFFFFFFu - (unsigned)(key & 0xFFFFFFFFull);
            unsigned flat = anchor * C_ + (unsigned)c;
            keepkeys[(size_t)gcls * MAXK + nk] =
                (key & 0xFFFFFFFF00000000ull) | (u64)(0xFFFFFFFFu - flat);
            kb[nk] = sb; ka[nk] = sa;
          }
          ++nk;
          if (nk >= MAXK) break;
          // suppress current word only (self-bit clears: self-IOU ~ 1 > 0.1)
          alive &= ~__ballot(iou_gt(sb.x, sb.y, sb.z, sb.w, sa, mb.x, mb.y, mb.z, mb.w, ma));
        }
        if (nk >= MAXK) break;
      }
      if (lane == 0) sh_nk = nk;
    }
    __syncthreads();
    ext += run;
    bhi = blo;
  }

  // ---- inline exact continuation (cold path) ----
  int nkF = sh_nk;
  if (nkF < MAXK) {
    float teff;
    if (overflow)     teff = 2.0f;
    else if (sh_over) teff = __uint_as_float(BINBASE + ((unsigned)bhi << BINSH) - 1u);
    else              teff = t0;
    const float* sbase = cls + (size_t)b * N_ * C_ + c;
    const float* bx = boxes + (size_t)b * N_ * 4;
    u64* kkp = keepkeys + (size_t)gcls * MAXK;
    int nk2 = nkF;
    while (nk2 < MAXK) {
      u64 best = 0ull;
      for (int n = tid; n < N_; n += 256) {
        float s = sbase[(size_t)n * C_];
        if (s > THR && s <= teff) {
          float y1 = bx[(size_t)n * 4 + 0], x1 = bx[(size_t)n * 4 + 1];
          float y2 = bx[(size_t)n * 4 + 2], x2 = bx[(size_t)n * 4 + 3];
          float ar = area_of(y1, x1, y2, x2);
          bool ov = false;
          for (int j = 0; j < nk2; ++j) {
            float4 kbj = kb[j];
            if (iou_gt(kbj.x, kbj.y, kbj.z, kbj.w, ka[j], y1, x1, y2, x2, ar)) { ov = true; break; }
          }
          if (!ov) {
            u64 key = ((u64)__float_as_uint(s) << 32) | (u64)(0xFFFFFFFFu - (unsigned)n);
            best = umax64(best, key);
          }
        }
      }
      red[tid] = best;
      __syncthreads();
      for (int sft = 128; sft > 0; sft >>= 1) {
        if (tid < sft) red[tid] = umax64(red[tid], red[tid + sft]);
        __syncthreads();
      }
      u64 sel = red[0];
      __syncthreads();
      if (sel == 0ull) {
        if (tid == 0) {  // exhausted before MAXK: reference quirk -> keep[anchor 0] = False
          unsigned target = 0xFFFFFFFFu - (unsigned)c;  // anchor 0 -> flat == c
          for (int j = 0; j < nk2; ++j)
            if ((unsigned)(kkp[j] & 0xFFFFFFFFull) == target) kkp[j] = 0ull;
        }
        break;
      }
      unsigned anchor = 0xFFFFFFFFu - (unsigned)(sel & 0xFFFFFFFFull);
      if (tid == 0) {
        float y1 = bx[(size_t)anchor * 4 + 0], x1 = bx[(size_t)anchor * 4 + 1];
        float y2 = bx[(size_t)anchor * 4 + 2], x2 = bx[(size_t)anchor * 4 + 3];
        kb[nk2] = make_float4(y1, x1, y2, x2);
        ka[nk2] = area_of(y1, x1, y2, x2);
        unsigned flat = anchor * C_ + (unsigned)c;
        kkp[nk2] = (sel & 0xFFFFFFFF00000000ull) | (u64)(0xFFFFFFFFu - flat);
      }
      ++nk2;
      __syncthreads();
    }
    nkF = nk2;
  }
  if (tid == 0) nk_arr[gcls] = nkF;
}

// ---------- kernel C: histogram-threshold top-100 (exact; serial fallback for tie floods) ----------
__global__ __launch_bounds__(256) void merge_kernel(const float* __restrict__ boxes,
                                                    const u64* __restrict__ keepkeys,
                                                    const int* __restrict__ nk_arr,
                                                    float* __restrict__ out) {
  int b = blockIdx.x;
  int tid = threadIdx.x;
  int lane = tid & 63;
  int wid = tid >> 6;
  __shared__ unsigned hist[NBIN];
  __shared__ unsigned sfx[NBIN];
  __shared__ unsigned wsum[4];
  __shared__ u64 mk[512];
  __shared__ u64 selk[MAXK];
  __shared__ int sh_thr;
  __shared__ unsigned sh_cc;
  const u64* kk = keepkeys + (size_t)b * C_ * MAXK;
  const int TOT = C_ * MAXK;           // 9000

  for (int i = tid; i < NBIN; i += 256) hist[i] = 0u;
  if (tid == 0) { sh_thr = -1; sh_cc = 0u; }
  __syncthreads();
  for (int i = tid; i < TOT; i += 256) {
    u64 k = kk[i];
    if (k != 0ull) atomicAdd(&hist[key2bin(k)], 1u);
  }
  __syncthreads();

  // suffix counts S[bin] = #keys in bins >= bin, via wave scan over reversed stripes
  const int W = 9;
  int j0 = tid * W;
  unsigned psum = 0;
#pragma unroll
  for (int q = 0; q < W; ++q) {
    int bin = NBIN - 1 - (j0 + q);
    if (bin >= 0) psum += hist[bin];
  }
  unsigned incl = psum;
#pragma unroll
  for (int s = 1; s < 64; s <<= 1) {
    unsigned v = (unsigned)__shfl_up((int)incl, s);
    if (lane >= s) incl += v;
  }
  if (lane == 63) wsum[wid] = incl;
  __syncthreads();
  unsigned base = 0;
  for (int w2 = 0; w2 < wid; ++w2) base += wsum[w2];
  unsigned running = base + incl - psum;
  int mythr = -1;
#pragma unroll
  for (int q = 0; q < W; ++q) {
    int bin = NBIN - 1 - (j0 + q);
    if (bin >= 0) {
      running += hist[bin];
      sfx[bin] = running;
      if (mythr < 0 && running >= (unsigned)MAXK) mythr = bin;  // largest qualifying in stripe
    }
  }
  if (mythr >= 0) atomicMax(&sh_thr, mythr);
  __syncthreads();

  int thr = sh_thr; if (thr < 0) thr = 0;
  unsigned S = sfx[thr];               // total candidates at/above threshold bin

  if (S <= 512u) {
    // fast path: compact + full bitonic sort (exact full-key order)
    for (int i = tid; i < TOT; i += 256) {
      u64 k = kk[i];
      if (k != 0ull && key2bin(k) >= thr) {
        unsigned pos = atomicAdd(&sh_cc, 1u);
        mk[pos] = k;
      }
    }
    __syncthreads();
    for (int i = (int)S + tid; i < 512; i += 256) mk[i] = 0ull;
    __syncthreads();
    for (int k2 = 2; k2 <= 512; k2 <<= 1) {
      for (int j = k2 >> 1; j > 0; j >>= 1) {
        int i1 = 2 * tid - (tid & (j - 1));
        int i2 = i1 | j;
        u64 a = mk[i1], bb2 = mk[i2];
        bool desc = ((i1 & k2) == 0);
        bool sw = desc ? (a < bb2) : (a > bb2);
        if (sw) { mk[i1] = bb2; mk[i2] = a; }
        __syncthreads();
      }
    }
    for (int r = tid; r < MAXK; r += 256) selk[r] = mk[r];
    __syncthreads();
  } else {
    // degenerate tie flood: exact serial tournament on wave 0
    if (wid == 0) {
      int c0 = lane, c1 = lane + 64;
      int len0 = (c0 < C_) ? nk_arr[b * C_ + c0] : 0;
      int len1 = (c1 < C_) ? nk_arr[b * C_ + c1] : 0;
      int h0 = 0, h1 = 0;
      auto fetchc = [&](int cc, int& h, int len) -> u64 {
        while (h < len) {
          u64 k = kk[(size_t)cc * MAXK + h];
          if (k != 0ull) return k;
          ++h;
        }
        return 0ull;
      };
      u64 cand0 = (c0 < C_) ? fetchc(c0, h0, len0) : 0ull;
      u64 cand1 = (c1 < C_) ? fetchc(c1, h1, len1) : 0ull;
      for (int r = 0; r < MAXK; ++r) {
        u64 my = umax64(cand0, cand1);
        u64 g = my;
#pragma unroll
        for (int m = 1; m < 64; m <<= 1) g = umax64(g, shfl_xor_u64(g, m));
        if (lane == 0) selk[r] = g;
        if (g != 0ull && my == g) {
          if (cand0 == g) { ++h0; cand0 = fetchc(c0, h0, len0); }
          else            { ++h1; cand1 = fetchc(c1, h1, len1); }
        }
      }
    }
    __syncthreads();
  }

  for (int r = tid; r < MAXK; r += 256) {
    u64 s = selk[r];
    float oy1, ox1, oy2, ox2, sc, lb;
    if (s != 0ull) {
      unsigned flat = 0xFFFFFFFFu - (unsigned)(s & 0xFFFFFFFFull);
      unsigned anchor = flat / C_;
      unsigned label = flat - anchor * C_;
      sc = __uint_as_float((unsigned)(s >> 32));
      const float4 bp = ((const float4*)(boxes + (size_t)b * N_ * 4))[anchor];
      oy1 = bp.x; ox1 = bp.y; oy2 = bp.z; ox2 = bp.w;
      lb = (float)label;
    } else {
      oy1 = ox1 = oy2 = ox2 = -1.0f; sc = -1.0f; lb = -1.0f;
    }
    float* bo = out + ((size_t)b * MAXK + r) * 4;
    bo[0] = oy1; bo[1] = ox1; bo[2] = oy2; bo[3] = ox2;
    out[(size_t)B_ * MAXK * 4 + b * MAXK + r] = sc;
    out[(size_t)B_ * MAXK * 4 + B_ * MAXK + b * MAXK + r] = lb;
  }
}

extern "C" void kernel_launch(void* const* d_in, const int* in_sizes, int n_in,
                              void* d_out, int out_size, void* d_ws, size_t ws_size,
                              hipStream_t stream) {
  const float* boxes = (const float*)d_in[0];   // [B,N,4]
  const float* cls = (const float*)d_in[1];     // [B,N,C]
  char* ws = (char*)d_ws;

  // capacity/threshold tiers by available workspace (all t0 >= 0.93 for BINBASE validity)
  int capsel; float t0;
  auto need_for = [](int cap) -> size_t {
    return 23040 + (size_t)NCLS * cap * 8 + 288000 + 1440;
  };
  if (ws_size >= need_for(4096))      { capsel = 4096; t0 = 0.93f;  }  // M ~ 3437 +/- 57
  else if (ws_size >= need_for(2048)) { capsel = 2048; t0 = 0.962f; }  // M ~ 1866 +/- 42
  else                                { capsel = 1024; t0 = 0.985f; }  // M ~  737 +/- 27

  unsigned* cnt = (unsigned*)ws;                      // 360 counters, 64B padded
  u64* keybuf = (u64*)(ws + 23040);
  size_t off = 23040 + (size_t)NCLS * capsel * 8;
  u64* keepkeys = (u64*)(ws + off);      off += 288000;
  int* nk_arr = (int*)(ws + off);

  hipMemsetAsync(cnt, 0, 23040, stream);
  select_kernel<<<B_ * NCH, 256, 0, stream>>>(cls, keybuf, cnt, capsel, t0);
  nms_kernel<<<NCLS, 256, 0, stream>>>(boxes, cls, keybuf, cnt, capsel, t0,
                                       keepkeys, nk_arr);
  merge_kernel<<<B_, 256, 0, stream>>>(boxes, keepkeys, nk_arr, (float*)d_out);
}